// Round 1
// baseline (483.524 us; speedup 1.0000x reference)
//
#include <hip/hip_runtime.h>

// HGIN_classifier: two relational-GIN layers (R=2), ReLU between.
// R15: B-hoist experiment. R14's gemm showed MfmaUtil 9.9 / VALUBusy 19.5 /
// HBM 6.5% — latency-bound, not pipe-bound. Cause: B (w1t) loaded from
// global INSIDE the K-loop with only 80 VGPRs allocated -> ~1 iter of
// lookahead -> 12 exposed L2 round-trips (~250cy each) per wave vs 480cy
// of MFMA. Fix: hoist all 48 B frags (f16x8 x 12ks x 4nt = 192 VGPR) into
// registers BEFORE the staging barrier; the vmcnt(0) drain for the A-DMA
// hides their L2 latency. __launch_bounds__(256,6): LDS (24.6KB -> 6
// blocks/CU = 6 waves/SIMD) caps occupancy anyway, so allow ~341 VGPR.
// K-loop is now pure ds_read_b128 + MFMA.
// Pipeline: zero_small -> bucketB -> bscan -> bucketC
//           cvt_all -> aggregate -> gemm_mfma -> gather2

typedef _Float16 f16;
typedef _Float16 f16x2 __attribute__((ext_vector_type(2)));
typedef _Float16 f16x4 __attribute__((ext_vector_type(4)));
typedef _Float16 f16x8 __attribute__((ext_vector_type(8)));
typedef float    f32x4 __attribute__((ext_vector_type(4)));
typedef __attribute__((address_space(3))) void       as3_void;
typedef __attribute__((address_space(1))) const void as1_cvoid;

constexpr int NN   = 100000;
constexpr int NR   = NN * 2;     // (node, relation) segments
constexpr int NB   = 512;        // coarse buckets (only 391 populated)
constexpr int BSH  = 9;          // bucket = seg >> BSH (512 segs/bucket)
constexpr int CAP  = 5120;       // slots/bucket: mean 4096, +16 sigma
constexpr int CHUNK = 2048;      // edges per block in bucketB (782 blocks)

__global__ void zero_small(int* __restrict__ gbase) {
  int t = threadIdx.x;
  if (t < NB) gbase[t] = t * CAP;
}

// packed edge: (src << 9) | (seg & 511)   [src < 2^23, fits int]
// scatter into capacity-strided ebuf; gbase[b] ends at b*CAP + count(b).
__global__ void bucketB(const int* __restrict__ src, const int* __restrict__ dst,
                        const int* __restrict__ et, int* __restrict__ gbase,
                        int* __restrict__ ebuf, int E) {
  __shared__ int h[NB], base[NB];
  int t = threadIdx.x;
  for (int b = t; b < NB; b += 256) h[b] = 0;
  __syncthreads();
  int lo = blockIdx.x * CHUNK, hi = min(E, lo + CHUNK);
  for (int e = lo + t; e < hi; e += 256)
    atomicAdd(&h[(dst[e] * 2 + et[e]) >> BSH], 1);
  __syncthreads();
  for (int b = t; b < NB; b += 256) {
    int c = h[b];
    base[b] = c ? atomicAdd(&gbase[b], c) : 0;
    h[b] = 0;
  }
  __syncthreads();
  for (int e = lo + t; e < hi; e += 256) {
    int seg = dst[e] * 2 + et[e];
    int b = seg >> BSH;
    int r = atomicAdd(&h[b], 1);
    ebuf[base[b] + r] = (src[e] << BSH) | (seg & (NB - 1));
  }
}

// dense prefix over bucket counts: bstart[b] = sum_{<b} (gbase - b*CAP)
__global__ void bscan(const int* __restrict__ gbase, int* __restrict__ bstart) {
  __shared__ int s[NB];
  int t = threadIdx.x;
  int v = gbase[t] - t * CAP;
  s[t] = v;
  __syncthreads();
  #pragma unroll
  for (int o = 1; o < NB; o <<= 1) {
    int u = (t >= o) ? s[t - o] : 0;
    __syncthreads();
    s[t] += u;
    __syncthreads();
  }
  bstart[t] = s[t] - v;
  if (t == NB - 1) bstart[NB] = s[t];
}

// One block per bucket: CSR off (dense, start-based) + dense srcs scatter.
__global__ void bucketC(const int* __restrict__ ebuf, const int* __restrict__ gbase,
                        const int* __restrict__ bstart,
                        int* __restrict__ off, int* __restrict__ srcs) {
  __shared__ int sh[NB], soff[NB], cnt[NB], tmp[256];
  int b = blockIdx.x, t = threadIdx.x;
  int lo = b * CAP, hi = gbase[b];
  int obase = bstart[b];
  for (int s0 = t; s0 < NB; s0 += 256) { sh[s0] = 0; cnt[s0] = 0; }
  __syncthreads();
  for (int e = lo + t; e < hi; e += 256)
    atomicAdd(&sh[ebuf[e] & (NB - 1)], 1);
  __syncthreads();
  int a0 = sh[2 * t], a1 = sh[2 * t + 1];
  tmp[t] = a0 + a1;
  __syncthreads();
  #pragma unroll
  for (int o = 1; o < 256; o <<= 1) {
    int u = (t >= o) ? tmp[t - o] : 0;
    __syncthreads();
    tmp[t] += u;
    __syncthreads();
  }
  int ex = tmp[t] - (a0 + a1);
  soff[2 * t] = ex;
  soff[2 * t + 1] = ex + a0;
  __syncthreads();
  int g0 = (b << BSH) + 2 * t;
  if (g0 <= NR)     off[g0]     = obase + soff[2 * t];
  if (g0 + 1 <= NR) off[g0 + 1] = obase + soff[2 * t + 1];
  for (int e = lo + t; e < hi; e += 256) {
    int p = ebuf[e];
    int s = p & (NB - 1);
    int r = atomicAdd(&cnt[s], 1);
    srcs[obase + soff[s] + r] = ((unsigned)p) >> BSH;
  }
}

// merged cast: x -> f16 and W1 -> k-step-major f16 repack.
// w1t[ks][n][ki] = f16(W[ks*32+ki][n]).
__global__ void cvt_all(const float4* __restrict__ xf, f16* __restrict__ xh,
                        const float* __restrict__ w1s, const float* __restrict__ w1r,
                        f16* __restrict__ w1t, int n4) {
  int i = blockIdx.x * blockDim.x + threadIdx.x;
  if (i < n4) {
    float4 v = xf[i];
    f16x4 h;
    h.x = (f16)v.x; h.y = (f16)v.y; h.z = (f16)v.z; h.w = (f16)v.w;
    *(f16x4*)(xh + (size_t)i * 4) = h;
  } else {
    int id = i - n4;
    if (id < 12 * 256 * 32) {
      int ks = id >> 13, rem = id & 8191;
      int n = rem >> 5, ki = rem & 31;
      int k = ks * 32 + ki;
      float v = (k < 128) ? w1s[k * 256 + n] : w1r[(k - 128) * 256 + n];
      w1t[id] = (f16)v;
    }
  }
}

// One wave per node. Lane-half h=lane>>5 processes edge e+h: one instruction
// loads 2 rows (32 lanes x f16x4 = 256B each). Halves merged via shfl_xor(32).
__global__ void aggregate(const f16* __restrict__ xh, const int* __restrict__ off,
                          const int* __restrict__ srcs, f16* __restrict__ aggh) {
  int w = (blockIdx.x * blockDim.x + threadIdx.x) >> 6;
  if (w >= NN) return;
  int lane = threadIdx.x & 63;
  int h = lane >> 5, c = lane & 31;
  int e0 = off[2 * w];
  int e1 = off[2 * w + 1];
  int e2 = off[2 * w + 2];
  float ax = 0.f, ay = 0.f, az = 0.f, aw = 0.f;
  float bx = 0.f, by = 0.f, bz = 0.f, bw = 0.f;

  int e = e0;
  for (; e + 7 < e1; e += 8) {
    f16x4 v0 = *(const f16x4*)(xh + (long)srcs[e     + h] * 128 + c * 4);
    f16x4 v1 = *(const f16x4*)(xh + (long)srcs[e + 2 + h] * 128 + c * 4);
    f16x4 v2 = *(const f16x4*)(xh + (long)srcs[e + 4 + h] * 128 + c * 4);
    f16x4 v3 = *(const f16x4*)(xh + (long)srcs[e + 6 + h] * 128 + c * 4);
    ax += (float)v0.x + (float)v1.x + (float)v2.x + (float)v3.x;
    ay += (float)v0.y + (float)v1.y + (float)v2.y + (float)v3.y;
    az += (float)v0.z + (float)v1.z + (float)v2.z + (float)v3.z;
    aw += (float)v0.w + (float)v1.w + (float)v2.w + (float)v3.w;
  }
  for (; e + 1 < e1; e += 2) {
    f16x4 v = *(const f16x4*)(xh + (long)srcs[e + h] * 128 + c * 4);
    ax += (float)v.x; ay += (float)v.y; az += (float)v.z; aw += (float)v.w;
  }
  if (e < e1) {
    f16x4 v = *(const f16x4*)(xh + (long)srcs[e] * 128 + c * 4);
    if (h == 0) { ax += (float)v.x; ay += (float)v.y; az += (float)v.z; aw += (float)v.w; }
  }
  e = e1;
  for (; e + 7 < e2; e += 8) {
    f16x4 v0 = *(const f16x4*)(xh + (long)srcs[e     + h] * 128 + c * 4);
    f16x4 v1 = *(const f16x4*)(xh + (long)srcs[e + 2 + h] * 128 + c * 4);
    f16x4 v2 = *(const f16x4*)(xh + (long)srcs[e + 4 + h] * 128 + c * 4);
    f16x4 v3 = *(const f16x4*)(xh + (long)srcs[e + 6 + h] * 128 + c * 4);
    bx += (float)v0.x + (float)v1.x + (float)v2.x + (float)v3.x;
    by += (float)v0.y + (float)v1.y + (float)v2.y + (float)v3.y;
    bz += (float)v0.z + (float)v1.z + (float)v2.z + (float)v3.z;
    bw += (float)v0.w + (float)v1.w + (float)v2.w + (float)v3.w;
  }
  for (; e + 1 < e2; e += 2) {
    f16x4 v = *(const f16x4*)(xh + (long)srcs[e + h] * 128 + c * 4);
    bx += (float)v.x; by += (float)v.y; bz += (float)v.z; bw += (float)v.w;
  }
  if (e < e2) {
    f16x4 v = *(const f16x4*)(xh + (long)srcs[e] * 128 + c * 4);
    if (h == 0) { bx += (float)v.x; by += (float)v.y; bz += (float)v.z; bw += (float)v.w; }
  }

  ax += __shfl_xor(ax, 32); ay += __shfl_xor(ay, 32);
  az += __shfl_xor(az, 32); aw += __shfl_xor(aw, 32);
  bx += __shfl_xor(bx, 32); by += __shfl_xor(by, 32);
  bz += __shfl_xor(bz, 32); bw += __shfl_xor(bw, 32);

  f16* row = aggh + (long)w * 256;
  f16x4 o;
  if (h == 0) {
    o.x = (f16)ax; o.y = (f16)ay; o.z = (f16)az; o.w = (f16)aw;
    *(f16x4*)(row + c * 4) = o;
  } else {
    o.x = (f16)bx; o.y = (f16)by; o.z = (f16)bz; o.w = (f16)bw;
    *(f16x4*)(row + 128 + c * 4) = o;
  }
}

// Fused layer-1 GEMM (f16 MFMA) + layer-2 transform epilogue.
// 32-row tile: A (32r x 384k = 24 KB) staged upfront via global_load_lds as
// 12 slabs x 2 KB; wave wv issues 6 DMA instrs ((slab,half) pairs). ALL 48
// B fragments (12ks x 4nt x f16x8 = 192 VGPR) hoisted into registers before
// the barrier — their L2 latency hides under the A-DMA vmcnt(0) drain, and
// the barrier pins the loads early (compiler can't sink a global load across
// __syncthreads). ONE barrier, then barrier-free K-loop that is pure
// ds_read_b128 (XOR chunk swizzle, conflict-free) + MFMA.
// Grid 3125 (NN/32 exact — no tail masks). 4 waves, wave = 32r x 64c
// (acc 2x4 f32x4 = 32 VGPR). 24.6KB LDS -> 6 blocks/CU = 24 waves/CU;
// launch_bounds(256,6) matches that (VGPR cap ~341 > ~250 needed).
// Fragment layouts (m89/m120-verified): A: m=lane&15, k=quad*8+j;
// B: n=lane&15, k=quad*8+j; C/D: col=lane&15, row=quad*4+reg.
__global__ __launch_bounds__(256, 6) void gemm_mfma(
    const f16* __restrict__ xh, const f16* __restrict__ aggh,
    const f16* __restrict__ w1t,
    const float* __restrict__ b1, const float* __restrict__ w2s,
    const float* __restrict__ w2r, const float* __restrict__ b2,
    float* __restrict__ z2, float* __restrict__ out) {
  __shared__ __align__(16) f16 Ash[12 * 1024];    // 12 slabs x 2 KB = 24 KB
  float (*zbuf)[32][6] = (float (*)[32][6])(void*)Ash;  // aliased (3 KB)
  const int t = threadIdx.x;
  const int lane = t & 63, wv = t >> 6;
  const int ml = lane & 15, quad = lane >> 4;
  const int cphi = quad ^ ((ml >> 1) & 3);        // swizzled chunk for frags
  const long rowBase = (long)blockIdx.x * 32;

  // ---- upfront A staging: 24 wave-level DMA instrs, 6 per wave.
  // linear g = wv*6+i -> slab = g>>1, half = g&1; lane's physical slot
  // s = half*64+lane -> row r=s>>2, logical chunk cl=(s&3)^((r>>1)&3).
  #pragma unroll
  for (int i = 0; i < 6; ++i) {
    int g = wv * 6 + i;
    int slab = g >> 1, half = g & 1;
    int s = half * 64 + lane;
    int r = s >> 2;
    int cl = (s & 3) ^ ((r >> 1) & 3);
    long grow = rowBase + r;
    const f16* ap = (slab < 4)
        ? (xh + grow * 128 + slab * 32 + cl * 8)
        : (aggh + grow * 256 + (slab - 4) * 32 + cl * 8);
    __builtin_amdgcn_global_load_lds((const as1_cvoid*)ap,
                                     (as3_void*)&Ash[slab * 1024 + half * 512],
                                     16, 0, 0);
  }

  // ---- hoist ALL B fragments into registers (48 x f16x8 = 192 VGPR).
  // Issued before the barrier: the vmcnt(0) drain for the A-DMA (HBM,
  // ~900cy) covers the B L2 latency (~300cy) for free.
  const f16* bwv = w1t + (long)(wv * 64 + ml) * 32 + quad * 8;
  f16x8 bf[12][4];
  #pragma unroll
  for (int ks = 0; ks < 12; ++ks)
    #pragma unroll
    for (int nt = 0; nt < 4; ++nt)
      bf[ks][nt] = *(const f16x8*)(bwv + (long)ks * 8192 + nt * 512);

  __syncthreads();                                  // drains DMA + B loads

  // ---- barrier-free K-loop: pure ds_read + MFMA, zero VMEM
  f32x4 acc[2][4];
  #pragma unroll
  for (int mt = 0; mt < 2; ++mt)
    #pragma unroll
    for (int nt = 0; nt < 4; ++nt) acc[mt][nt] = (f32x4)(0.f);

  #pragma unroll
  for (int ks = 0; ks < 12; ++ks) {
    f16x8 af[2];
    #pragma unroll
    for (int mt = 0; mt < 2; ++mt)
      af[mt] = *(const f16x8*)&Ash[ks * 1024 + ((mt * 16 + ml) * 4 + cphi) * 8];
    #pragma unroll
    for (int mt = 0; mt < 2; ++mt)
      #pragma unroll
      for (int nt = 0; nt < 4; ++nt)
        acc[mt][nt] = __builtin_amdgcn_mfma_f32_16x16x32_f16(af[mt], bf[ks][nt],
                                                             acc[mt][nt], 0, 0, 0);
  }
  __syncthreads();   // all Ash reads done before zbuf (aliased) writes

  // Epilogue: h = relu(acc + b1[col]); 6 dots over this wave's 64 cols;
  // reduce over the 16 ml-lanes; partials to zbuf[wv] (aliased onto Ash).
  #pragma unroll
  for (int mt = 0; mt < 2; ++mt) {
    float z[4][6];
    #pragma unroll
    for (int rr = 0; rr < 4; ++rr)
      #pragma unroll
      for (int p = 0; p < 6; ++p) z[rr][p] = 0.f;
    #pragma unroll
    for (int nt = 0; nt < 4; ++nt) {
      int col = wv * 64 + nt * 16 + ml;
      float bb = b1[col];
      float wA = w2r[col * 2 + 0];
      float wB = w2r[col * 2 + 1];
      float wC = w2r[512 + col * 2 + 0];
      float wD = w2r[512 + col * 2 + 1];
      float wE = w2s[col * 2 + 0];
      float wF = w2s[col * 2 + 1];
      #pragma unroll
      for (int rr = 0; rr < 4; ++rr) {
        float hh = acc[mt][nt][rr] + bb;
        hh = hh > 0.f ? hh : 0.f;
        z[rr][0] = fmaf(hh, wA, z[rr][0]);
        z[rr][1] = fmaf(hh, wB, z[rr][1]);
        z[rr][2] = fmaf(hh, wC, z[rr][2]);
        z[rr][3] = fmaf(hh, wD, z[rr][3]);
        z[rr][4] = fmaf(hh, wE, z[rr][4]);
        z[rr][5] = fmaf(hh, wF, z[rr][5]);
      }
    }
    #pragma unroll
    for (int rr = 0; rr < 4; ++rr)
      #pragma unroll
      for (int p = 0; p < 6; ++p) {
        float v = z[rr][p];
        v += __shfl_xor(v, 1);
        v += __shfl_xor(v, 2);
        v += __shfl_xor(v, 4);
        v += __shfl_xor(v, 8);
        if (ml == 0) zbuf[wv][mt * 16 + quad * 4 + rr][p] = v;
      }
  }
  __syncthreads();
  if (t < 192) {
    int r = t / 6, p = t % 6;
    long grow = rowBase + r;
    float v = zbuf[0][r][p] + zbuf[1][r][p] + zbuf[2][r][p] + zbuf[3][r][p];
    if (p < 4) z2[grow * 4 + p] = v;
    else       out[grow * 2 + (p - 4)] = v + b2[p - 4];
  }
}

// 4 lanes per node: lane sub handles every-4th edge; reduce over sub.
__global__ void gather2(const float* __restrict__ z2, const int* __restrict__ off,
                        const int* __restrict__ srcs, float* __restrict__ out) {
  int tid = blockIdx.x * blockDim.x + threadIdx.x;
  int n = tid >> 2;
  if (n >= NN) return;
  int sub = tid & 3;
  int e0 = off[2 * n];
  int e1 = off[2 * n + 1];
  int e2 = off[2 * n + 2];
  float o0 = 0.f, o1 = 0.f;
  for (int e = e0 + sub; e < e1; e += 4) {
    float2 v = *(const float2*)(z2 + (long)srcs[e] * 4);
    o0 += v.x; o1 += v.y;
  }
  for (int e = e1 + sub; e < e2; e += 4) {
    float2 v = *(const float2*)(z2 + (long)srcs[e] * 4 + 2);
    o0 += v.x; o1 += v.y;
  }
  o0 += __shfl_xor(o0, 1); o1 += __shfl_xor(o1, 1);
  o0 += __shfl_xor(o0, 2); o1 += __shfl_xor(o1, 2);
  if (sub == 0) {
    out[n * 2 + 0] += o0;
    out[n * 2 + 1] += o1;
  }
}

extern "C" void kernel_launch(void* const* d_in, const int* in_sizes, int n_in,
                              void* d_out, int out_size, void* d_ws, size_t ws_size,
                              hipStream_t stream) {
  const float* x   = (const float*)d_in[0];
  const int*   ei  = (const int*)d_in[1];
  const int*   et  = (const int*)d_in[2];
  const float* w1s = (const float*)d_in[3];
  const float* w1r = (const float*)d_in[4];
  const float* b1  = (const float*)d_in[5];
  const float* w2s = (const float*)d_in[6];
  const float* w2r = (const float*)d_in[7];
  const float* b2  = (const float*)d_in[8];
  float* out = (float*)d_out;
  const int E = in_sizes[2];
  const int* src = ei;
  const int* dst = ei + E;

  f16*   aggh = (f16*)d_ws;                      // NN*256 f16   (51.2 MB)
  f16*   xh   = aggh + (size_t)NN * 256;         // NN*128 f16   (25.6 MB)
  f16*   w1t  = xh + (size_t)NN * 128;           // 12*256*32 f16 (0.2 MB)
  float* z2   = (float*)(w1t + 12 * 256 * 32);   // NN*4 f32     (1.6 MB)
  int*   ebuf = (int*)(z2 + (size_t)NN * 4);     // NB*CAP int   (10.5 MB)
  int*   srcs = ebuf + (size_t)NB * CAP;         // E int        (6.4 MB)
  int*   off  = srcs + E;                        // NR+1 int     (0.8 MB)
  int*   gbase  = off + NR + 1;                  // NB int
  int*   bstart = gbase + NB;                    // NB+1 int

  int nblk = (E + CHUNK - 1) / CHUNK;
  zero_small<<<1, 512, 0, stream>>>(gbase);
  bucketB<<<nblk, 256, 0, stream>>>(src, dst, et, gbase, ebuf, E);
  bscan<<<1, 512, 0, stream>>>(gbase, bstart);
  bucketC<<<NB, 256, 0, stream>>>(ebuf, gbase, bstart, off, srcs);

  int n4 = NN * 128 / 4;
  int ncvt = n4 + 12 * 256 * 32;
  cvt_all<<<(ncvt + 255) / 256, 256, 0, stream>>>((const float4*)x, xh,
                                                  w1s, w1r, w1t, n4);

  aggregate<<<(NN * 64 + 255) / 256, 256, 0, stream>>>(xh, off, srcs, aggh);

  gemm_mfma<<<NN / 32, 256, 0, stream>>>(xh, aggh, w1t, b1, w2s, w2r, b2,
                                         z2, out);

  gather2<<<(NN * 4 + 255) / 256, 256, 0, stream>>>(z2, off, srcs, out);
}

// Round 2
// 385.492 us; speedup vs baseline: 1.2543x; 1.2543x over previous
//
#include <hip/hip_runtime.h>

// HGIN_classifier: two relational-GIN layers (R=2), ReLU between.
// R16: persistent-block gemm with B fully register-resident.
// R15 post-mortem: __launch_bounds__(256,6) caps VGPR at 512/6=85, so the
// 192-reg B hoist spilled wholesale to scratch (VGPR_Count 40, WRITE_SIZE
// 446MB, 226us). Correct budget: 2 waves/SIMD -> cap 256 VGPR.
// R16 design: grid 512 (exactly 2 blocks/CU at 256 VGPR), each block owns
// ~6 contiguous 32-row tiles. B (w1t, 48 x f16x8 = 192 VGPR) loaded ONCE
// per wave and held across tiles (kills both the per-ks L2 latency that
// made R14's MfmaUtil 9.9%, and 5/6 of the 600MB aggregate B L2 traffic).
// A double-buffered in LDS (2x24KB + 3KB zbuf = 51KB), counted vmcnt(6) +
// raw s_barrier per tile so next-tile DMA stays in flight across barriers
// (m201 T3/T4 pattern). K-loop is pure ds_read_b128 + MFMA.
// Pipeline: zero_small -> bucketB -> bscan -> bucketC
//           cvt_all -> aggregate -> gemm_persist -> gather2

typedef _Float16 f16;
typedef _Float16 f16x2 __attribute__((ext_vector_type(2)));
typedef _Float16 f16x4 __attribute__((ext_vector_type(4)));
typedef _Float16 f16x8 __attribute__((ext_vector_type(8)));
typedef float    f32x4 __attribute__((ext_vector_type(4)));
typedef __attribute__((address_space(3))) void       as3_void;
typedef __attribute__((address_space(1))) const void as1_cvoid;

constexpr int NN   = 100000;
constexpr int NR   = NN * 2;     // (node, relation) segments
constexpr int NB   = 512;        // coarse buckets (only 391 populated)
constexpr int BSH  = 9;          // bucket = seg >> BSH (512 segs/bucket)
constexpr int CAP  = 5120;       // slots/bucket: mean 4096, +16 sigma
constexpr int CHUNK = 2048;      // edges per block in bucketB (782 blocks)
constexpr int GB   = 512;        // persistent gemm blocks (2/CU, all resident)
constexpr int NT   = NN / 32;    // 3125 tiles

__global__ void zero_small(int* __restrict__ gbase) {
  int t = threadIdx.x;
  if (t < NB) gbase[t] = t * CAP;
}

// packed edge: (src << 9) | (seg & 511)   [src < 2^23, fits int]
// scatter into capacity-strided ebuf; gbase[b] ends at b*CAP + count(b).
__global__ void bucketB(const int* __restrict__ src, const int* __restrict__ dst,
                        const int* __restrict__ et, int* __restrict__ gbase,
                        int* __restrict__ ebuf, int E) {
  __shared__ int h[NB], base[NB];
  int t = threadIdx.x;
  for (int b = t; b < NB; b += 256) h[b] = 0;
  __syncthreads();
  int lo = blockIdx.x * CHUNK, hi = min(E, lo + CHUNK);
  for (int e = lo + t; e < hi; e += 256)
    atomicAdd(&h[(dst[e] * 2 + et[e]) >> BSH], 1);
  __syncthreads();
  for (int b = t; b < NB; b += 256) {
    int c = h[b];
    base[b] = c ? atomicAdd(&gbase[b], c) : 0;
    h[b] = 0;
  }
  __syncthreads();
  for (int e = lo + t; e < hi; e += 256) {
    int seg = dst[e] * 2 + et[e];
    int b = seg >> BSH;
    int r = atomicAdd(&h[b], 1);
    ebuf[base[b] + r] = (src[e] << BSH) | (seg & (NB - 1));
  }
}

// dense prefix over bucket counts: bstart[b] = sum_{<b} (gbase - b*CAP)
__global__ void bscan(const int* __restrict__ gbase, int* __restrict__ bstart) {
  __shared__ int s[NB];
  int t = threadIdx.x;
  int v = gbase[t] - t * CAP;
  s[t] = v;
  __syncthreads();
  #pragma unroll
  for (int o = 1; o < NB; o <<= 1) {
    int u = (t >= o) ? s[t - o] : 0;
    __syncthreads();
    s[t] += u;
    __syncthreads();
  }
  bstart[t] = s[t] - v;
  if (t == NB - 1) bstart[NB] = s[t];
}

// One block per bucket: CSR off (dense, start-based) + dense srcs scatter.
__global__ void bucketC(const int* __restrict__ ebuf, const int* __restrict__ gbase,
                        const int* __restrict__ bstart,
                        int* __restrict__ off, int* __restrict__ srcs) {
  __shared__ int sh[NB], soff[NB], cnt[NB], tmp[256];
  int b = blockIdx.x, t = threadIdx.x;
  int lo = b * CAP, hi = gbase[b];
  int obase = bstart[b];
  for (int s0 = t; s0 < NB; s0 += 256) { sh[s0] = 0; cnt[s0] = 0; }
  __syncthreads();
  for (int e = lo + t; e < hi; e += 256)
    atomicAdd(&sh[ebuf[e] & (NB - 1)], 1);
  __syncthreads();
  int a0 = sh[2 * t], a1 = sh[2 * t + 1];
  tmp[t] = a0 + a1;
  __syncthreads();
  #pragma unroll
  for (int o = 1; o < 256; o <<= 1) {
    int u = (t >= o) ? tmp[t - o] : 0;
    __syncthreads();
    tmp[t] += u;
    __syncthreads();
  }
  int ex = tmp[t] - (a0 + a1);
  soff[2 * t] = ex;
  soff[2 * t + 1] = ex + a0;
  __syncthreads();
  int g0 = (b << BSH) + 2 * t;
  if (g0 <= NR)     off[g0]     = obase + soff[2 * t];
  if (g0 + 1 <= NR) off[g0 + 1] = obase + soff[2 * t + 1];
  for (int e = lo + t; e < hi; e += 256) {
    int p = ebuf[e];
    int s = p & (NB - 1);
    int r = atomicAdd(&cnt[s], 1);
    srcs[obase + soff[s] + r] = ((unsigned)p) >> BSH;
  }
}

// merged cast: x -> f16 and W1 -> k-step-major f16 repack.
// w1t[ks][n][ki] = f16(W[ks*32+ki][n]).
__global__ void cvt_all(const float4* __restrict__ xf, f16* __restrict__ xh,
                        const float* __restrict__ w1s, const float* __restrict__ w1r,
                        f16* __restrict__ w1t, int n4) {
  int i = blockIdx.x * blockDim.x + threadIdx.x;
  if (i < n4) {
    float4 v = xf[i];
    f16x4 h;
    h.x = (f16)v.x; h.y = (f16)v.y; h.z = (f16)v.z; h.w = (f16)v.w;
    *(f16x4*)(xh + (size_t)i * 4) = h;
  } else {
    int id = i - n4;
    if (id < 12 * 256 * 32) {
      int ks = id >> 13, rem = id & 8191;
      int n = rem >> 5, ki = rem & 31;
      int k = ks * 32 + ki;
      float v = (k < 128) ? w1s[k * 256 + n] : w1r[(k - 128) * 256 + n];
      w1t[id] = (f16)v;
    }
  }
}

// One wave per node. Lane-half h=lane>>5 processes edge e+h: one instruction
// loads 2 rows (32 lanes x f16x4 = 256B each). Halves merged via shfl_xor(32).
__global__ void aggregate(const f16* __restrict__ xh, const int* __restrict__ off,
                          const int* __restrict__ srcs, f16* __restrict__ aggh) {
  int w = (blockIdx.x * blockDim.x + threadIdx.x) >> 6;
  if (w >= NN) return;
  int lane = threadIdx.x & 63;
  int h = lane >> 5, c = lane & 31;
  int e0 = off[2 * w];
  int e1 = off[2 * w + 1];
  int e2 = off[2 * w + 2];
  float ax = 0.f, ay = 0.f, az = 0.f, aw = 0.f;
  float bx = 0.f, by = 0.f, bz = 0.f, bw = 0.f;

  int e = e0;
  for (; e + 7 < e1; e += 8) {
    f16x4 v0 = *(const f16x4*)(xh + (long)srcs[e     + h] * 128 + c * 4);
    f16x4 v1 = *(const f16x4*)(xh + (long)srcs[e + 2 + h] * 128 + c * 4);
    f16x4 v2 = *(const f16x4*)(xh + (long)srcs[e + 4 + h] * 128 + c * 4);
    f16x4 v3 = *(const f16x4*)(xh + (long)srcs[e + 6 + h] * 128 + c * 4);
    ax += (float)v0.x + (float)v1.x + (float)v2.x + (float)v3.x;
    ay += (float)v0.y + (float)v1.y + (float)v2.y + (float)v3.y;
    az += (float)v0.z + (float)v1.z + (float)v2.z + (float)v3.z;
    aw += (float)v0.w + (float)v1.w + (float)v2.w + (float)v3.w;
  }
  for (; e + 1 < e1; e += 2) {
    f16x4 v = *(const f16x4*)(xh + (long)srcs[e + h] * 128 + c * 4);
    ax += (float)v.x; ay += (float)v.y; az += (float)v.z; aw += (float)v.w;
  }
  if (e < e1) {
    f16x4 v = *(const f16x4*)(xh + (long)srcs[e] * 128 + c * 4);
    if (h == 0) { ax += (float)v.x; ay += (float)v.y; az += (float)v.z; aw += (float)v.w; }
  }
  e = e1;
  for (; e + 7 < e2; e += 8) {
    f16x4 v0 = *(const f16x4*)(xh + (long)srcs[e     + h] * 128 + c * 4);
    f16x4 v1 = *(const f16x4*)(xh + (long)srcs[e + 2 + h] * 128 + c * 4);
    f16x4 v2 = *(const f16x4*)(xh + (long)srcs[e + 4 + h] * 128 + c * 4);
    f16x4 v3 = *(const f16x4*)(xh + (long)srcs[e + 6 + h] * 128 + c * 4);
    bx += (float)v0.x + (float)v1.x + (float)v2.x + (float)v3.x;
    by += (float)v0.y + (float)v1.y + (float)v2.y + (float)v3.y;
    bz += (float)v0.z + (float)v1.z + (float)v2.z + (float)v3.z;
    bw += (float)v0.w + (float)v1.w + (float)v2.w + (float)v3.w;
  }
  for (; e + 1 < e2; e += 2) {
    f16x4 v = *(const f16x4*)(xh + (long)srcs[e + h] * 128 + c * 4);
    bx += (float)v.x; by += (float)v.y; bz += (float)v.z; bw += (float)v.w;
  }
  if (e < e2) {
    f16x4 v = *(const f16x4*)(xh + (long)srcs[e] * 128 + c * 4);
    if (h == 0) { bx += (float)v.x; by += (float)v.y; bz += (float)v.z; bw += (float)v.w; }
  }

  ax += __shfl_xor(ax, 32); ay += __shfl_xor(ay, 32);
  az += __shfl_xor(az, 32); aw += __shfl_xor(aw, 32);
  bx += __shfl_xor(bx, 32); by += __shfl_xor(by, 32);
  bz += __shfl_xor(bz, 32); bw += __shfl_xor(bw, 32);

  f16* row = aggh + (long)w * 256;
  f16x4 o;
  if (h == 0) {
    o.x = (f16)ax; o.y = (f16)ay; o.z = (f16)az; o.w = (f16)aw;
    *(f16x4*)(row + c * 4) = o;
  } else {
    o.x = (f16)bx; o.y = (f16)by; o.z = (f16)bz; o.w = (f16)bw;
    *(f16x4*)(row + 128 + c * 4) = o;
  }
}

// Issue this wave's 6 A-staging DMAs for one 32-row tile into LDS buffer dst.
// linear g = wv*6+i -> slab = g>>1, half = g&1; lane's physical slot
// s = half*64+lane -> row r=s>>2, logical chunk cl=(s&3)^((r>>1)&3)
// (XOR source swizzle matched by cphi on the read side).
__device__ __forceinline__ void stage_tile(const f16* __restrict__ xh,
                                           const f16* __restrict__ aggh,
                                           f16* dst, long rowBase,
                                           int wv, int lane) {
  #pragma unroll
  for (int i = 0; i < 6; ++i) {
    int g = wv * 6 + i;
    int slab = g >> 1, half = g & 1;
    int s = half * 64 + lane;
    int r = s >> 2;
    int cl = (s & 3) ^ ((r >> 1) & 3);
    long grow = rowBase + r;
    const f16* ap = (slab < 4)
        ? (xh + grow * 128 + slab * 32 + cl * 8)
        : (aggh + grow * 256 + (slab - 4) * 32 + cl * 8);
    __builtin_amdgcn_global_load_lds((const as1_cvoid*)ap,
                                     (as3_void*)&dst[slab * 1024 + half * 512],
                                     16, 0, 0);
  }
}

// Persistent fused layer-1 GEMM (f16 MFMA) + layer-2 transform epilogue.
// 512 blocks (2/CU, all resident). Block owns ntiles (~6) contiguous 32-row
// tiles. B: 48 x f16x8 = 192 VGPR, loaded once, live across tiles. A:
// double-buffered LDS (2 x 24KB); per tile each wave issues 6 DMA for the
// NEXT tile, then s_waitcnt vmcnt(6) (own newest 6 outstanding = next tile;
// current tile + anything older drained) + raw s_barrier -> all waves' DMAs
// for the current tile have landed, next-tile loads stay in flight.
// K-loop: pure ds_read_b128 + MFMA. launch_bounds(256,2) -> VGPR cap 256.
// Fragment layouts (m89/m120-verified): A: m=lane&15, k=quad*8+j;
// B: n=lane&15, k=quad*8+j; C/D: col=lane&15, row=quad*4+reg.
__global__ __launch_bounds__(256, 2) void gemm_persist(
    const f16* __restrict__ xh, const f16* __restrict__ aggh,
    const f16* __restrict__ w1t,
    const float* __restrict__ b1, const float* __restrict__ w2s,
    const float* __restrict__ w2r, const float* __restrict__ b2,
    float* __restrict__ z2, float* __restrict__ out) {
  __shared__ __align__(16) f16 Ash[2][12 * 1024];   // 2 x 24 KB
  __shared__ float zbuf[4][32][6];                   // 3 KB (not aliased)
  const int t = threadIdx.x;
  const int lane = t & 63, wv = t >> 6;
  const int ml = lane & 15, quad = lane >> 4;
  const int cphi = quad ^ ((ml >> 1) & 3);           // swizzled chunk for frags
  const int bid = blockIdx.x;
  const int ntiles = 6 + (bid < NT - GB * 6 ? 1 : 0);          // 53 blocks get 7
  const int tile0  = bid * 6 + (bid < NT - GB * 6 ? bid : NT - GB * 6);

  // ---- prologue: stage tile0 into buf0, then hoist ALL B fragments.
  stage_tile(xh, aggh, &Ash[0][0], (long)tile0 * 32, wv, lane);

  const f16* bwv = w1t + (long)(wv * 64 + ml) * 32 + quad * 8;
  f16x8 bf[12][4];
  #pragma unroll
  for (int ks = 0; ks < 12; ++ks)
    #pragma unroll
    for (int nt = 0; nt < 4; ++nt)
      bf[ks][nt] = *(const f16x8*)(bwv + (long)ks * 8192 + nt * 512);

  for (int i = 0; i < ntiles; ++i) {
    const long rowBase = (long)(tile0 + i) * 32;
    // issue next tile's DMA into the other buffer (stays in flight across
    // the barrier — counted vmcnt, never drain to 0 mid-loop)
    if (i + 1 < ntiles)
      stage_tile(xh, aggh, &Ash[(i + 1) & 1][0], rowBase + 32, wv, lane);
    asm volatile("s_waitcnt vmcnt(6)" ::: "memory");
    __builtin_amdgcn_s_barrier();

    // ---- K-loop: pure ds_read + MFMA (B already in registers)
    const f16* Ab = &Ash[i & 1][0];
    f32x4 acc[2][4];
    #pragma unroll
    for (int mt = 0; mt < 2; ++mt)
      #pragma unroll
      for (int nt = 0; nt < 4; ++nt) acc[mt][nt] = (f32x4)(0.f);

    #pragma unroll
    for (int ks = 0; ks < 12; ++ks) {
      f16x8 af[2];
      #pragma unroll
      for (int mt = 0; mt < 2; ++mt)
        af[mt] = *(const f16x8*)&Ab[ks * 1024 + ((mt * 16 + ml) * 4 + cphi) * 8];
      #pragma unroll
      for (int mt = 0; mt < 2; ++mt)
        #pragma unroll
        for (int nt = 0; nt < 4; ++nt)
          acc[mt][nt] = __builtin_amdgcn_mfma_f32_16x16x32_f16(af[mt], bf[ks][nt],
                                                               acc[mt][nt], 0, 0, 0);
    }

    // Epilogue: h = relu(acc + b1[col]); 6 dots over this wave's 64 cols;
    // reduce over the 16 ml-lanes; partials to zbuf[wv].
    #pragma unroll
    for (int mt = 0; mt < 2; ++mt) {
      float z[4][6];
      #pragma unroll
      for (int rr = 0; rr < 4; ++rr)
        #pragma unroll
        for (int p = 0; p < 6; ++p) z[rr][p] = 0.f;
      #pragma unroll
      for (int nt = 0; nt < 4; ++nt) {
        int col = wv * 64 + nt * 16 + ml;
        float bb = b1[col];
        float wA = w2r[col * 2 + 0];
        float wB = w2r[col * 2 + 1];
        float wC = w2r[512 + col * 2 + 0];
        float wD = w2r[512 + col * 2 + 1];
        float wE = w2s[col * 2 + 0];
        float wF = w2s[col * 2 + 1];
        #pragma unroll
        for (int rr = 0; rr < 4; ++rr) {
          float hh = acc[mt][nt][rr] + bb;
          hh = hh > 0.f ? hh : 0.f;
          z[rr][0] = fmaf(hh, wA, z[rr][0]);
          z[rr][1] = fmaf(hh, wB, z[rr][1]);
          z[rr][2] = fmaf(hh, wC, z[rr][2]);
          z[rr][3] = fmaf(hh, wD, z[rr][3]);
          z[rr][4] = fmaf(hh, wE, z[rr][4]);
          z[rr][5] = fmaf(hh, wF, z[rr][5]);
        }
      }
      #pragma unroll
      for (int rr = 0; rr < 4; ++rr)
        #pragma unroll
        for (int p = 0; p < 6; ++p) {
          float v = z[rr][p];
          v += __shfl_xor(v, 1);
          v += __shfl_xor(v, 2);
          v += __shfl_xor(v, 4);
          v += __shfl_xor(v, 8);
          if (ml == 0) zbuf[wv][mt * 16 + quad * 4 + rr][p] = v;
        }
    }
    __builtin_amdgcn_s_barrier();
    if (t < 192) {
      int r = t / 6, p = t % 6;
      long grow = rowBase + r;
      float v = zbuf[0][r][p] + zbuf[1][r][p] + zbuf[2][r][p] + zbuf[3][r][p];
      if (p < 4) z2[grow * 4 + p] = v;
      else       out[grow * 2 + (p - 4)] = v + b2[p - 4];
    }
    // zbuf WAR across iterations: next iter's zbuf writes happen only after
    // its post-vmcnt s_barrier, which the storing waves reach only after
    // their zbuf reads completed (store data dep). Same barrier covers the
    // A-buffer WAR (all ds_reads of buf[i&1] done before it is re-DMA'd).
  }
}

// 4 lanes per node: lane sub handles every-4th edge; reduce over sub.
__global__ void gather2(const float* __restrict__ z2, const int* __restrict__ off,
                        const int* __restrict__ srcs, float* __restrict__ out) {
  int tid = blockIdx.x * blockDim.x + threadIdx.x;
  int n = tid >> 2;
  if (n >= NN) return;
  int sub = tid & 3;
  int e0 = off[2 * n];
  int e1 = off[2 * n + 1];
  int e2 = off[2 * n + 2];
  float o0 = 0.f, o1 = 0.f;
  for (int e = e0 + sub; e < e1; e += 4) {
    float2 v = *(const float2*)(z2 + (long)srcs[e] * 4);
    o0 += v.x; o1 += v.y;
  }
  for (int e = e1 + sub; e < e2; e += 4) {
    float2 v = *(const float2*)(z2 + (long)srcs[e] * 4 + 2);
    o0 += v.x; o1 += v.y;
  }
  o0 += __shfl_xor(o0, 1); o1 += __shfl_xor(o1, 1);
  o0 += __shfl_xor(o0, 2); o1 += __shfl_xor(o1, 2);
  if (sub == 0) {
    out[n * 2 + 0] += o0;
    out[n * 2 + 1] += o1;
  }
}

extern "C" void kernel_launch(void* const* d_in, const int* in_sizes, int n_in,
                              void* d_out, int out_size, void* d_ws, size_t ws_size,
                              hipStream_t stream) {
  const float* x   = (const float*)d_in[0];
  const int*   ei  = (const int*)d_in[1];
  const int*   et  = (const int*)d_in[2];
  const float* w1s = (const float*)d_in[3];
  const float* w1r = (const float*)d_in[4];
  const float* b1  = (const float*)d_in[5];
  const float* w2s = (const float*)d_in[6];
  const float* w2r = (const float*)d_in[7];
  const float* b2  = (const float*)d_in[8];
  float* out = (float*)d_out;
  const int E = in_sizes[2];
  const int* src = ei;
  const int* dst = ei + E;

  f16*   aggh = (f16*)d_ws;                      // NN*256 f16   (51.2 MB)
  f16*   xh   = aggh + (size_t)NN * 256;         // NN*128 f16   (25.6 MB)
  f16*   w1t  = xh + (size_t)NN * 128;           // 12*256*32 f16 (0.2 MB)
  float* z2   = (float*)(w1t + 12 * 256 * 32);   // NN*4 f32     (1.6 MB)
  int*   ebuf = (int*)(z2 + (size_t)NN * 4);     // NB*CAP int   (10.5 MB)
  int*   srcs = ebuf + (size_t)NB * CAP;         // E int        (6.4 MB)
  int*   off  = srcs + E;                        // NR+1 int     (0.8 MB)
  int*   gbase  = off + NR + 1;                  // NB int
  int*   bstart = gbase + NB;                    // NB+1 int

  int nblk = (E + CHUNK - 1) / CHUNK;
  zero_small<<<1, 512, 0, stream>>>(gbase);
  bucketB<<<nblk, 256, 0, stream>>>(src, dst, et, gbase, ebuf, E);
  bscan<<<1, 512, 0, stream>>>(gbase, bstart);
  bucketC<<<NB, 256, 0, stream>>>(ebuf, gbase, bstart, off, srcs);

  int n4 = NN * 128 / 4;
  int ncvt = n4 + 12 * 256 * 32;
  cvt_all<<<(ncvt + 255) / 256, 256, 0, stream>>>((const float4*)x, xh,
                                                  w1s, w1r, w1t, n4);

  aggregate<<<(NN * 64 + 255) / 256, 256, 0, stream>>>(xh, off, srcs, aggh);

  gemm_persist<<<GB, 256, 0, stream>>>(xh, aggh, w1t, b1, w2s, w2r, b2,
                                       z2, out);

  gather2<<<(NN * 4 + 255) / 256, 256, 0, stream>>>(z2, off, srcs, out);
}

// Round 3
// 378.971 us; speedup vs baseline: 1.2759x; 1.0172x over previous
//
#include <hip/hip_runtime.h>

// HGIN_classifier: two relational-GIN layers (R=2), ReLU between.
// R17: persistent gemm, 8 waves x 32 cols -> B hoist = 96 VGPR (allocatable).
// R16 post-mortem: 192-VGPR B array spilled (~56 regs: VGPR_Count 128,
// WRITE_SIZE 31.5MB vs 2.4MB floor) even at cap 256 — allocator splits big
// live-across-loop arrays. Fix: 512-thread blocks, 8 waves, 32 cols/wave:
// bf[12][2] = 96 VGPR + acc 16 + af 8 + addr ~30 = ~150 < 256 cap
// (launch_bounds(512,2), 1 block/CU, grid 256, ~12.2 tiles/block).
// Also fixed R16 race: last tile must drain with vmcnt(0) (no next stage to
// count against), and explicit lgkmcnt(0) before zbuf barriers.
// Cost model: K-loop now LDS-throughput-bound (~1us/tile/CU), B read once
// (49MB total vs R14's 614MB L2 traffic + per-ks latency).
// Pipeline: zero_small -> bucketB -> bscan -> bucketC
//           cvt_all -> aggregate -> gemm_persist -> gather2

typedef _Float16 f16;
typedef _Float16 f16x2 __attribute__((ext_vector_type(2)));
typedef _Float16 f16x4 __attribute__((ext_vector_type(4)));
typedef _Float16 f16x8 __attribute__((ext_vector_type(8)));
typedef float    f32x4 __attribute__((ext_vector_type(4)));
typedef __attribute__((address_space(3))) void       as3_void;
typedef __attribute__((address_space(1))) const void as1_cvoid;

constexpr int NN   = 100000;
constexpr int NR   = NN * 2;     // (node, relation) segments
constexpr int NB   = 512;        // coarse buckets (only 391 populated)
constexpr int BSH  = 9;          // bucket = seg >> BSH (512 segs/bucket)
constexpr int CAP  = 5120;       // slots/bucket: mean 4096, +16 sigma
constexpr int CHUNK = 2048;      // edges per block in bucketB (782 blocks)
constexpr int GB   = 256;        // persistent gemm blocks (1/CU, 512 thr)
constexpr int NT   = NN / 32;    // 3125 tiles
constexpr int TPB  = NT / GB;    // 12 tiles/block base (remainder 53)

__global__ void zero_small(int* __restrict__ gbase) {
  int t = threadIdx.x;
  if (t < NB) gbase[t] = t * CAP;
}

// packed edge: (src << 9) | (seg & 511)   [src < 2^23, fits int]
// scatter into capacity-strided ebuf; gbase[b] ends at b*CAP + count(b).
__global__ void bucketB(const int* __restrict__ src, const int* __restrict__ dst,
                        const int* __restrict__ et, int* __restrict__ gbase,
                        int* __restrict__ ebuf, int E) {
  __shared__ int h[NB], base[NB];
  int t = threadIdx.x;
  for (int b = t; b < NB; b += 256) h[b] = 0;
  __syncthreads();
  int lo = blockIdx.x * CHUNK, hi = min(E, lo + CHUNK);
  for (int e = lo + t; e < hi; e += 256)
    atomicAdd(&h[(dst[e] * 2 + et[e]) >> BSH], 1);
  __syncthreads();
  for (int b = t; b < NB; b += 256) {
    int c = h[b];
    base[b] = c ? atomicAdd(&gbase[b], c) : 0;
    h[b] = 0;
  }
  __syncthreads();
  for (int e = lo + t; e < hi; e += 256) {
    int seg = dst[e] * 2 + et[e];
    int b = seg >> BSH;
    int r = atomicAdd(&h[b], 1);
    ebuf[base[b] + r] = (src[e] << BSH) | (seg & (NB - 1));
  }
}

// dense prefix over bucket counts: bstart[b] = sum_{<b} (gbase - b*CAP)
__global__ void bscan(const int* __restrict__ gbase, int* __restrict__ bstart) {
  __shared__ int s[NB];
  int t = threadIdx.x;
  int v = gbase[t] - t * CAP;
  s[t] = v;
  __syncthreads();
  #pragma unroll
  for (int o = 1; o < NB; o <<= 1) {
    int u = (t >= o) ? s[t - o] : 0;
    __syncthreads();
    s[t] += u;
    __syncthreads();
  }
  bstart[t] = s[t] - v;
  if (t == NB - 1) bstart[NB] = s[t];
}

// One block per bucket: CSR off (dense, start-based) + dense srcs scatter.
__global__ void bucketC(const int* __restrict__ ebuf, const int* __restrict__ gbase,
                        const int* __restrict__ bstart,
                        int* __restrict__ off, int* __restrict__ srcs) {
  __shared__ int sh[NB], soff[NB], cnt[NB], tmp[256];
  int b = blockIdx.x, t = threadIdx.x;
  int lo = b * CAP, hi = gbase[b];
  int obase = bstart[b];
  for (int s0 = t; s0 < NB; s0 += 256) { sh[s0] = 0; cnt[s0] = 0; }
  __syncthreads();
  for (int e = lo + t; e < hi; e += 256)
    atomicAdd(&sh[ebuf[e] & (NB - 1)], 1);
  __syncthreads();
  int a0 = sh[2 * t], a1 = sh[2 * t + 1];
  tmp[t] = a0 + a1;
  __syncthreads();
  #pragma unroll
  for (int o = 1; o < 256; o <<= 1) {
    int u = (t >= o) ? tmp[t - o] : 0;
    __syncthreads();
    tmp[t] += u;
    __syncthreads();
  }
  int ex = tmp[t] - (a0 + a1);
  soff[2 * t] = ex;
  soff[2 * t + 1] = ex + a0;
  __syncthreads();
  int g0 = (b << BSH) + 2 * t;
  if (g0 <= NR)     off[g0]     = obase + soff[2 * t];
  if (g0 + 1 <= NR) off[g0 + 1] = obase + soff[2 * t + 1];
  for (int e = lo + t; e < hi; e += 256) {
    int p = ebuf[e];
    int s = p & (NB - 1);
    int r = atomicAdd(&cnt[s], 1);
    srcs[obase + soff[s] + r] = ((unsigned)p) >> BSH;
  }
}

// merged cast: x -> f16 and W1 -> k-step-major f16 repack.
// w1t[ks][n][ki] = f16(W[ks*32+ki][n]).
__global__ void cvt_all(const float4* __restrict__ xf, f16* __restrict__ xh,
                        const float* __restrict__ w1s, const float* __restrict__ w1r,
                        f16* __restrict__ w1t, int n4) {
  int i = blockIdx.x * blockDim.x + threadIdx.x;
  if (i < n4) {
    float4 v = xf[i];
    f16x4 h;
    h.x = (f16)v.x; h.y = (f16)v.y; h.z = (f16)v.z; h.w = (f16)v.w;
    *(f16x4*)(xh + (size_t)i * 4) = h;
  } else {
    int id = i - n4;
    if (id < 12 * 256 * 32) {
      int ks = id >> 13, rem = id & 8191;
      int n = rem >> 5, ki = rem & 31;
      int k = ks * 32 + ki;
      float v = (k < 128) ? w1s[k * 256 + n] : w1r[(k - 128) * 256 + n];
      w1t[id] = (f16)v;
    }
  }
}

// One wave per node. Lane-half h=lane>>5 processes edge e+h: one instruction
// loads 2 rows (32 lanes x f16x4 = 256B each). Halves merged via shfl_xor(32).
__global__ void aggregate(const f16* __restrict__ xh, const int* __restrict__ off,
                          const int* __restrict__ srcs, f16* __restrict__ aggh) {
  int w = (blockIdx.x * blockDim.x + threadIdx.x) >> 6;
  if (w >= NN) return;
  int lane = threadIdx.x & 63;
  int h = lane >> 5, c = lane & 31;
  int e0 = off[2 * w];
  int e1 = off[2 * w + 1];
  int e2 = off[2 * w + 2];
  float ax = 0.f, ay = 0.f, az = 0.f, aw = 0.f;
  float bx = 0.f, by = 0.f, bz = 0.f, bw = 0.f;

  int e = e0;
  for (; e + 7 < e1; e += 8) {
    f16x4 v0 = *(const f16x4*)(xh + (long)srcs[e     + h] * 128 + c * 4);
    f16x4 v1 = *(const f16x4*)(xh + (long)srcs[e + 2 + h] * 128 + c * 4);
    f16x4 v2 = *(const f16x4*)(xh + (long)srcs[e + 4 + h] * 128 + c * 4);
    f16x4 v3 = *(const f16x4*)(xh + (long)srcs[e + 6 + h] * 128 + c * 4);
    ax += (float)v0.x + (float)v1.x + (float)v2.x + (float)v3.x;
    ay += (float)v0.y + (float)v1.y + (float)v2.y + (float)v3.y;
    az += (float)v0.z + (float)v1.z + (float)v2.z + (float)v3.z;
    aw += (float)v0.w + (float)v1.w + (float)v2.w + (float)v3.w;
  }
  for (; e + 1 < e1; e += 2) {
    f16x4 v = *(const f16x4*)(xh + (long)srcs[e + h] * 128 + c * 4);
    ax += (float)v.x; ay += (float)v.y; az += (float)v.z; aw += (float)v.w;
  }
  if (e < e1) {
    f16x4 v = *(const f16x4*)(xh + (long)srcs[e] * 128 + c * 4);
    if (h == 0) { ax += (float)v.x; ay += (float)v.y; az += (float)v.z; aw += (float)v.w; }
  }
  e = e1;
  for (; e + 7 < e2; e += 8) {
    f16x4 v0 = *(const f16x4*)(xh + (long)srcs[e     + h] * 128 + c * 4);
    f16x4 v1 = *(const f16x4*)(xh + (long)srcs[e + 2 + h] * 128 + c * 4);
    f16x4 v2 = *(const f16x4*)(xh + (long)srcs[e + 4 + h] * 128 + c * 4);
    f16x4 v3 = *(const f16x4*)(xh + (long)srcs[e + 6 + h] * 128 + c * 4);
    bx += (float)v0.x + (float)v1.x + (float)v2.x + (float)v3.x;
    by += (float)v0.y + (float)v1.y + (float)v2.y + (float)v3.y;
    bz += (float)v0.z + (float)v1.z + (float)v2.z + (float)v3.z;
    bw += (float)v0.w + (float)v1.w + (float)v2.w + (float)v3.w;
  }
  for (; e + 1 < e2; e += 2) {
    f16x4 v = *(const f16x4*)(xh + (long)srcs[e + h] * 128 + c * 4);
    bx += (float)v.x; by += (float)v.y; bz += (float)v.z; bw += (float)v.w;
  }
  if (e < e2) {
    f16x4 v = *(const f16x4*)(xh + (long)srcs[e] * 128 + c * 4);
    if (h == 0) { bx += (float)v.x; by += (float)v.y; bz += (float)v.z; bw += (float)v.w; }
  }

  ax += __shfl_xor(ax, 32); ay += __shfl_xor(ay, 32);
  az += __shfl_xor(az, 32); aw += __shfl_xor(aw, 32);
  bx += __shfl_xor(bx, 32); by += __shfl_xor(by, 32);
  bz += __shfl_xor(bz, 32); bw += __shfl_xor(bw, 32);

  f16* row = aggh + (long)w * 256;
  f16x4 o;
  if (h == 0) {
    o.x = (f16)ax; o.y = (f16)ay; o.z = (f16)az; o.w = (f16)aw;
    *(f16x4*)(row + c * 4) = o;
  } else {
    o.x = (f16)bx; o.y = (f16)by; o.z = (f16)bz; o.w = (f16)bw;
    *(f16x4*)(row + 128 + c * 4) = o;
  }
}

// Issue this wave's 3 A-staging DMAs for one 32-row tile into LDS buffer dst
// (8 waves x 3 = 24 x 1KB units = 24KB tile). linear g = wv*3+i ->
// slab = g>>1, half = g&1; lane's physical slot s = half*64+lane ->
// row r=s>>2, logical chunk cl=(s&3)^((r>>1)&3) (XOR source swizzle matched
// by cphi on the read side).
__device__ __forceinline__ void stage_tile(const f16* __restrict__ xh,
                                           const f16* __restrict__ aggh,
                                           f16* dst, long rowBase,
                                           int wv, int lane) {
  #pragma unroll
  for (int i = 0; i < 3; ++i) {
    int g = wv * 3 + i;
    int slab = g >> 1, half = g & 1;
    int s = half * 64 + lane;
    int r = s >> 2;
    int cl = (s & 3) ^ ((r >> 1) & 3);
    long grow = rowBase + r;
    const f16* ap = (slab < 4)
        ? (xh + grow * 128 + slab * 32 + cl * 8)
        : (aggh + grow * 256 + (slab - 4) * 32 + cl * 8);
    __builtin_amdgcn_global_load_lds((const as1_cvoid*)ap,
                                     (as3_void*)&dst[slab * 1024 + half * 512],
                                     16, 0, 0);
  }
}

// Persistent fused layer-1 GEMM (f16 MFMA) + layer-2 transform epilogue.
// 256 blocks x 512 threads (1/CU). 8 waves, wave = 32 rows x 32 cols
// (acc 2x2, bf[12][2] = 96 VGPR live across all ~12 tiles). A double-
// buffered LDS (2 x 24KB); per tile each wave issues 3 DMA for the NEXT
// tile, then s_waitcnt vmcnt(3) + s_barrier (counted vmcnt: next-tile loads
// stay in flight across the barrier). Last tile drains vmcnt(0).
// Fragment layouts (m89/m120-verified): A: m=lane&15, k=quad*8+j;
// B: n=lane&15, k=quad*8+j; C/D: col=lane&15, row=quad*4+reg.
__global__ __launch_bounds__(512, 2) void gemm_persist(
    const f16* __restrict__ xh, const f16* __restrict__ aggh,
    const f16* __restrict__ w1t,
    const float* __restrict__ b1, const float* __restrict__ w2s,
    const float* __restrict__ w2r, const float* __restrict__ b2,
    float* __restrict__ z2, float* __restrict__ out) {
  __shared__ __align__(16) f16 Ash[2][12 * 1024];   // 2 x 24 KB
  __shared__ float zbuf[8][32][6];                   // 6 KB
  const int t = threadIdx.x;
  const int lane = t & 63, wv = t >> 6;
  const int ml = lane & 15, quad = lane >> 4;
  const int cphi = quad ^ ((ml >> 1) & 3);           // swizzled chunk for frags
  const int bid = blockIdx.x;
  const int rem = NT - GB * TPB;                     // 53
  const int ntiles = TPB + (bid < rem ? 1 : 0);
  const int tile0  = bid * TPB + (bid < rem ? bid : rem);

  // ---- prologue: stage tile0 into buf0, then hoist B (96 VGPR).
  stage_tile(xh, aggh, &Ash[0][0], (long)tile0 * 32, wv, lane);

  const f16* bwv = w1t + (long)(wv * 32 + ml) * 32 + quad * 8;
  f16x8 bf[12][2];
  #pragma unroll
  for (int ks = 0; ks < 12; ++ks)
    #pragma unroll
    for (int nt = 0; nt < 2; ++nt)
      bf[ks][nt] = *(const f16x8*)(bwv + (long)ks * 8192 + nt * 512);

  for (int i = 0; i < ntiles; ++i) {
    const long rowBase = (long)(tile0 + i) * 32;
    // issue next tile's DMA into the other buffer; counted vmcnt keeps them
    // in flight across the barrier. Last tile: full drain (R16 bug fixed).
    if (i + 1 < ntiles) {
      stage_tile(xh, aggh, &Ash[(i + 1) & 1][0], rowBase + 32, wv, lane);
      asm volatile("s_waitcnt vmcnt(3)" ::: "memory");
    } else {
      asm volatile("s_waitcnt vmcnt(0)" ::: "memory");
    }
    __builtin_amdgcn_s_barrier();

    // ---- K-loop: pure ds_read + MFMA (B already in registers)
    const f16* Ab = &Ash[i & 1][0];
    f32x4 acc[2][2];
    #pragma unroll
    for (int mt = 0; mt < 2; ++mt)
      #pragma unroll
      for (int nt = 0; nt < 2; ++nt) acc[mt][nt] = (f32x4)(0.f);

    #pragma unroll
    for (int ks = 0; ks < 12; ++ks) {
      f16x8 af[2];
      #pragma unroll
      for (int mt = 0; mt < 2; ++mt)
        af[mt] = *(const f16x8*)&Ab[ks * 1024 + ((mt * 16 + ml) * 4 + cphi) * 8];
      #pragma unroll
      for (int mt = 0; mt < 2; ++mt)
        #pragma unroll
        for (int nt = 0; nt < 2; ++nt)
          acc[mt][nt] = __builtin_amdgcn_mfma_f32_16x16x32_f16(af[mt], bf[ks][nt],
                                                               acc[mt][nt], 0, 0, 0);
    }

    // Epilogue: h = relu(acc + b1[col]); 6 dots over this wave's 32 cols;
    // reduce over the 16 ml-lanes; partials to zbuf[wv].
    #pragma unroll
    for (int mt = 0; mt < 2; ++mt) {
      float z[4][6];
      #pragma unroll
      for (int rr = 0; rr < 4; ++rr)
        #pragma unroll
        for (int p = 0; p < 6; ++p) z[rr][p] = 0.f;
      #pragma unroll
      for (int nt = 0; nt < 2; ++nt) {
        int col = wv * 32 + nt * 16 + ml;
        float bb = b1[col];
        float wA = w2r[col * 2 + 0];
        float wB = w2r[col * 2 + 1];
        float wC = w2r[512 + col * 2 + 0];
        float wD = w2r[512 + col * 2 + 1];
        float wE = w2s[col * 2 + 0];
        float wF = w2s[col * 2 + 1];
        #pragma unroll
        for (int rr = 0; rr < 4; ++rr) {
          float hh = acc[mt][nt][rr] + bb;
          hh = hh > 0.f ? hh : 0.f;
          z[rr][0] = fmaf(hh, wA, z[rr][0]);
          z[rr][1] = fmaf(hh, wB, z[rr][1]);
          z[rr][2] = fmaf(hh, wC, z[rr][2]);
          z[rr][3] = fmaf(hh, wD, z[rr][3]);
          z[rr][4] = fmaf(hh, wE, z[rr][4]);
          z[rr][5] = fmaf(hh, wF, z[rr][5]);
        }
      }
      #pragma unroll
      for (int rr = 0; rr < 4; ++rr)
        #pragma unroll
        for (int p = 0; p < 6; ++p) {
          float v = z[rr][p];
          v += __shfl_xor(v, 1);
          v += __shfl_xor(v, 2);
          v += __shfl_xor(v, 4);
          v += __shfl_xor(v, 8);
          if (ml == 0) zbuf[wv][mt * 16 + quad * 4 + rr][p] = v;
        }
    }
    asm volatile("s_waitcnt lgkmcnt(0)" ::: "memory");  // zbuf writes visible
    __builtin_amdgcn_s_barrier();
    if (t < 192) {
      int r = t / 6, p = t % 6;
      long grow = rowBase + r;
      float v = zbuf[0][r][p] + zbuf[1][r][p] + zbuf[2][r][p] + zbuf[3][r][p]
              + zbuf[4][r][p] + zbuf[5][r][p] + zbuf[6][r][p] + zbuf[7][r][p];
      if (p < 4) z2[grow * 4 + p] = v;
      else       out[grow * 2 + (p - 4)] = v + b2[p - 4];
    }
    // WAR safety across iterations: next iter's stage targets the buffer
    // read two iterations ago; the vmcnt+barrier at next iter top orders
    // all waves' current reads before any re-DMA. zbuf WAR likewise
    // separated by that barrier (reads land in regs before barrier).
  }
}

// 4 lanes per node: lane sub handles every-4th edge; reduce over sub.
__global__ void gather2(const float* __restrict__ z2, const int* __restrict__ off,
                        const int* __restrict__ srcs, float* __restrict__ out) {
  int tid = blockIdx.x * blockDim.x + threadIdx.x;
  int n = tid >> 2;
  if (n >= NN) return;
  int sub = tid & 3;
  int e0 = off[2 * n];
  int e1 = off[2 * n + 1];
  int e2 = off[2 * n + 2];
  float o0 = 0.f, o1 = 0.f;
  for (int e = e0 + sub; e < e1; e += 4) {
    float2 v = *(const float2*)(z2 + (long)srcs[e] * 4);
    o0 += v.x; o1 += v.y;
  }
  for (int e = e1 + sub; e < e2; e += 4) {
    float2 v = *(const float2*)(z2 + (long)srcs[e] * 4 + 2);
    o0 += v.x; o1 += v.y;
  }
  o0 += __shfl_xor(o0, 1); o1 += __shfl_xor(o1, 1);
  o0 += __shfl_xor(o0, 2); o1 += __shfl_xor(o1, 2);
  if (sub == 0) {
    out[n * 2 + 0] += o0;
    out[n * 2 + 1] += o1;
  }
}

extern "C" void kernel_launch(void* const* d_in, const int* in_sizes, int n_in,
                              void* d_out, int out_size, void* d_ws, size_t ws_size,
                              hipStream_t stream) {
  const float* x   = (const float*)d_in[0];
  const int*   ei  = (const int*)d_in[1];
  const int*   et  = (const int*)d_in[2];
  const float* w1s = (const float*)d_in[3];
  const float* w1r = (const float*)d_in[4];
  const float* b1  = (const float*)d_in[5];
  const float* w2s = (const float*)d_in[6];
  const float* w2r = (const float*)d_in[7];
  const float* b2  = (const float*)d_in[8];
  float* out = (float*)d_out;
  const int E = in_sizes[2];
  const int* src = ei;
  const int* dst = ei + E;

  f16*   aggh = (f16*)d_ws;                      // NN*256 f16   (51.2 MB)
  f16*   xh   = aggh + (size_t)NN * 256;         // NN*128 f16   (25.6 MB)
  f16*   w1t  = xh + (size_t)NN * 128;           // 12*256*32 f16 (0.2 MB)
  float* z2   = (float*)(w1t + 12 * 256 * 32);   // NN*4 f32     (1.6 MB)
  int*   ebuf = (int*)(z2 + (size_t)NN * 4);     // NB*CAP int   (10.5 MB)
  int*   srcs = ebuf + (size_t)NB * CAP;         // E int        (6.4 MB)
  int*   off  = srcs + E;                        // NR+1 int     (0.8 MB)
  int*   gbase  = off + NR + 1;                  // NB int
  int*   bstart = gbase + NB;                    // NB+1 int

  int nblk = (E + CHUNK - 1) / CHUNK;
  zero_small<<<1, 512, 0, stream>>>(gbase);
  bucketB<<<nblk, 256, 0, stream>>>(src, dst, et, gbase, ebuf, E);
  bscan<<<1, 512, 0, stream>>>(gbase, bstart);
  bucketC<<<NB, 256, 0, stream>>>(ebuf, gbase, bstart, off, srcs);

  int n4 = NN * 128 / 4;
  int ncvt = n4 + 12 * 256 * 32;
  cvt_all<<<(ncvt + 255) / 256, 256, 0, stream>>>((const float4*)x, xh,
                                                  w1s, w1r, w1t, n4);

  aggregate<<<(NN * 64 + 255) / 256, 256, 0, stream>>>(xh, off, srcs, aggh);

  gemm_persist<<<GB, 512, 0, stream>>>(xh, aggh, w1t, b1, w2s, w2r, b2,
                                       z2, out);

  gather2<<<(NN * 4 + 255) / 256, 256, 0, stream>>>(z2, off, srcs, out);
}

// Round 5
// 370.778 us; speedup vs baseline: 1.3041x; 1.0221x over previous
//
#include <hip/hip_runtime.h>

// HGIN_classifier: two relational-GIN layers (R=2), ReLU between.
// R19: B pinned via identity-asm (safer variant of R18's opaque loads).
// R18 (hand-written asm global_load_dwordx4) never ran: container failed
// twice — can't rule out the handwritten VMEM asm faulting. Same theory,
// safer vehicle: NORMAL C++ loads of bf[12][2], then
// asm volatile("" : "+v"(bf)) per fragment. The volatile identity asm is
// position-pinned in the prologue; the load must complete before it; the
// loop consumes asm RESULTS, which LLVM cannot rematerialize -> bf must
// stay in VGPRs (cap 256 at launch_bounds(512,2); need ~160).
// R17 post-mortem recap: VGPR_Count=100 (< 140 floor for held bf) + clean
// WRITE_SIZE proved remat of read-only w1t loads into the tile loop =
// R14's latency disease (~10us/tile, MfmaUtil 6%).
// Falsification: VGPR stays ~100 (remat persisted) or WRITE_SIZE balloons
// (spill).
// Pipeline: zero_small -> bucketB -> bscan -> bucketC
//           cvt_all -> aggregate -> gemm_persist -> gather2

typedef _Float16 f16;
typedef _Float16 f16x2 __attribute__((ext_vector_type(2)));
typedef _Float16 f16x4 __attribute__((ext_vector_type(4)));
typedef _Float16 f16x8 __attribute__((ext_vector_type(8)));
typedef float    f32x4 __attribute__((ext_vector_type(4)));
typedef __attribute__((address_space(3))) void       as3_void;
typedef __attribute__((address_space(1))) const void as1_cvoid;

constexpr int NN   = 100000;
constexpr int NR   = NN * 2;     // (node, relation) segments
constexpr int NB   = 512;        // coarse buckets (only 391 populated)
constexpr int BSH  = 9;          // bucket = seg >> BSH (512 segs/bucket)
constexpr int CAP  = 5120;       // slots/bucket: mean 4096, +16 sigma
constexpr int CHUNK = 2048;      // edges per block in bucketB (782 blocks)
constexpr int GB   = 256;        // persistent gemm blocks (1/CU, 512 thr)
constexpr int NT   = NN / 32;    // 3125 tiles
constexpr int TPB  = NT / GB;    // 12 tiles/block base (remainder 53)

__global__ void zero_small(int* __restrict__ gbase) {
  int t = threadIdx.x;
  if (t < NB) gbase[t] = t * CAP;
}

// packed edge: (src << 9) | (seg & 511)   [src < 2^23, fits int]
// scatter into capacity-strided ebuf; gbase[b] ends at b*CAP + count(b).
__global__ void bucketB(const int* __restrict__ src, const int* __restrict__ dst,
                        const int* __restrict__ et, int* __restrict__ gbase,
                        int* __restrict__ ebuf, int E) {
  __shared__ int h[NB], base[NB];
  int t = threadIdx.x;
  for (int b = t; b < NB; b += 256) h[b] = 0;
  __syncthreads();
  int lo = blockIdx.x * CHUNK, hi = min(E, lo + CHUNK);
  for (int e = lo + t; e < hi; e += 256)
    atomicAdd(&h[(dst[e] * 2 + et[e]) >> BSH], 1);
  __syncthreads();
  for (int b = t; b < NB; b += 256) {
    int c = h[b];
    base[b] = c ? atomicAdd(&gbase[b], c) : 0;
    h[b] = 0;
  }
  __syncthreads();
  for (int e = lo + t; e < hi; e += 256) {
    int seg = dst[e] * 2 + et[e];
    int b = seg >> BSH;
    int r = atomicAdd(&h[b], 1);
    ebuf[base[b] + r] = (src[e] << BSH) | (seg & (NB - 1));
  }
}

// dense prefix over bucket counts: bstart[b] = sum_{<b} (gbase - b*CAP)
__global__ void bscan(const int* __restrict__ gbase, int* __restrict__ bstart) {
  __shared__ int s[NB];
  int t = threadIdx.x;
  int v = gbase[t] - t * CAP;
  s[t] = v;
  __syncthreads();
  #pragma unroll
  for (int o = 1; o < NB; o <<= 1) {
    int u = (t >= o) ? s[t - o] : 0;
    __syncthreads();
    s[t] += u;
    __syncthreads();
  }
  bstart[t] = s[t] - v;
  if (t == NB - 1) bstart[NB] = s[t];
}

// One block per bucket: CSR off (dense, start-based) + dense srcs scatter.
__global__ void bucketC(const int* __restrict__ ebuf, const int* __restrict__ gbase,
                        const int* __restrict__ bstart,
                        int* __restrict__ off, int* __restrict__ srcs) {
  __shared__ int sh[NB], soff[NB], cnt[NB], tmp[256];
  int b = blockIdx.x, t = threadIdx.x;
  int lo = b * CAP, hi = gbase[b];
  int obase = bstart[b];
  for (int s0 = t; s0 < NB; s0 += 256) { sh[s0] = 0; cnt[s0] = 0; }
  __syncthreads();
  for (int e = lo + t; e < hi; e += 256)
    atomicAdd(&sh[ebuf[e] & (NB - 1)], 1);
  __syncthreads();
  int a0 = sh[2 * t], a1 = sh[2 * t + 1];
  tmp[t] = a0 + a1;
  __syncthreads();
  #pragma unroll
  for (int o = 1; o < 256; o <<= 1) {
    int u = (t >= o) ? tmp[t - o] : 0;
    __syncthreads();
    tmp[t] += u;
    __syncthreads();
  }
  int ex = tmp[t] - (a0 + a1);
  soff[2 * t] = ex;
  soff[2 * t + 1] = ex + a0;
  __syncthreads();
  int g0 = (b << BSH) + 2 * t;
  if (g0 <= NR)     off[g0]     = obase + soff[2 * t];
  if (g0 + 1 <= NR) off[g0 + 1] = obase + soff[2 * t + 1];
  for (int e = lo + t; e < hi; e += 256) {
    int p = ebuf[e];
    int s = p & (NB - 1);
    int r = atomicAdd(&cnt[s], 1);
    srcs[obase + soff[s] + r] = ((unsigned)p) >> BSH;
  }
}

// merged cast: x -> f16 and W1 -> k-step-major f16 repack.
// w1t[ks][n][ki] = f16(W[ks*32+ki][n]).
__global__ void cvt_all(const float4* __restrict__ xf, f16* __restrict__ xh,
                        const float* __restrict__ w1s, const float* __restrict__ w1r,
                        f16* __restrict__ w1t, int n4) {
  int i = blockIdx.x * blockDim.x + threadIdx.x;
  if (i < n4) {
    float4 v = xf[i];
    f16x4 h;
    h.x = (f16)v.x; h.y = (f16)v.y; h.z = (f16)v.z; h.w = (f16)v.w;
    *(f16x4*)(xh + (size_t)i * 4) = h;
  } else {
    int id = i - n4;
    if (id < 12 * 256 * 32) {
      int ks = id >> 13, rem = id & 8191;
      int n = rem >> 5, ki = rem & 31;
      int k = ks * 32 + ki;
      float v = (k < 128) ? w1s[k * 256 + n] : w1r[(k - 128) * 256 + n];
      w1t[id] = (f16)v;
    }
  }
}

// One wave per node. Lane-half h=lane>>5 processes edge e+h: one instruction
// loads 2 rows (32 lanes x f16x4 = 256B each). Halves merged via shfl_xor(32).
__global__ void aggregate(const f16* __restrict__ xh, const int* __restrict__ off,
                          const int* __restrict__ srcs, f16* __restrict__ aggh) {
  int w = (blockIdx.x * blockDim.x + threadIdx.x) >> 6;
  if (w >= NN) return;
  int lane = threadIdx.x & 63;
  int h = lane >> 5, c = lane & 31;
  int e0 = off[2 * w];
  int e1 = off[2 * w + 1];
  int e2 = off[2 * w + 2];
  float ax = 0.f, ay = 0.f, az = 0.f, aw = 0.f;
  float bx = 0.f, by = 0.f, bz = 0.f, bw = 0.f;

  int e = e0;
  for (; e + 7 < e1; e += 8) {
    f16x4 v0 = *(const f16x4*)(xh + (long)srcs[e     + h] * 128 + c * 4);
    f16x4 v1 = *(const f16x4*)(xh + (long)srcs[e + 2 + h] * 128 + c * 4);
    f16x4 v2 = *(const f16x4*)(xh + (long)srcs[e + 4 + h] * 128 + c * 4);
    f16x4 v3 = *(const f16x4*)(xh + (long)srcs[e + 6 + h] * 128 + c * 4);
    ax += (float)v0.x + (float)v1.x + (float)v2.x + (float)v3.x;
    ay += (float)v0.y + (float)v1.y + (float)v2.y + (float)v3.y;
    az += (float)v0.z + (float)v1.z + (float)v2.z + (float)v3.z;
    aw += (float)v0.w + (float)v1.w + (float)v2.w + (float)v3.w;
  }
  for (; e + 1 < e1; e += 2) {
    f16x4 v = *(const f16x4*)(xh + (long)srcs[e + h] * 128 + c * 4);
    ax += (float)v.x; ay += (float)v.y; az += (float)v.z; aw += (float)v.w;
  }
  if (e < e1) {
    f16x4 v = *(const f16x4*)(xh + (long)srcs[e] * 128 + c * 4);
    if (h == 0) { ax += (float)v.x; ay += (float)v.y; az += (float)v.z; aw += (float)v.w; }
  }
  e = e1;
  for (; e + 7 < e2; e += 8) {
    f16x4 v0 = *(const f16x4*)(xh + (long)srcs[e     + h] * 128 + c * 4);
    f16x4 v1 = *(const f16x4*)(xh + (long)srcs[e + 2 + h] * 128 + c * 4);
    f16x4 v2 = *(const f16x4*)(xh + (long)srcs[e + 4 + h] * 128 + c * 4);
    f16x4 v3 = *(const f16x4*)(xh + (long)srcs[e + 6 + h] * 128 + c * 4);
    bx += (float)v0.x + (float)v1.x + (float)v2.x + (float)v3.x;
    by += (float)v0.y + (float)v1.y + (float)v2.y + (float)v3.y;
    bz += (float)v0.z + (float)v1.z + (float)v2.z + (float)v3.z;
    bw += (float)v0.w + (float)v1.w + (float)v2.w + (float)v3.w;
  }
  for (; e + 1 < e2; e += 2) {
    f16x4 v = *(const f16x4*)(xh + (long)srcs[e + h] * 128 + c * 4);
    bx += (float)v.x; by += (float)v.y; bz += (float)v.z; bw += (float)v.w;
  }
  if (e < e2) {
    f16x4 v = *(const f16x4*)(xh + (long)srcs[e] * 128 + c * 4);
    if (h == 0) { bx += (float)v.x; by += (float)v.y; bz += (float)v.z; bw += (float)v.w; }
  }

  ax += __shfl_xor(ax, 32); ay += __shfl_xor(ay, 32);
  az += __shfl_xor(az, 32); aw += __shfl_xor(aw, 32);
  bx += __shfl_xor(bx, 32); by += __shfl_xor(by, 32);
  bz += __shfl_xor(bz, 32); bw += __shfl_xor(bw, 32);

  f16* row = aggh + (long)w * 256;
  f16x4 o;
  if (h == 0) {
    o.x = (f16)ax; o.y = (f16)ay; o.z = (f16)az; o.w = (f16)aw;
    *(f16x4*)(row + c * 4) = o;
  } else {
    o.x = (f16)bx; o.y = (f16)by; o.z = (f16)bz; o.w = (f16)bw;
    *(f16x4*)(row + 128 + c * 4) = o;
  }
}

// Issue this wave's 3 A-staging DMAs for one 32-row tile into LDS buffer dst
// (8 waves x 3 = 24 x 1KB units = 24KB tile). linear g = wv*3+i ->
// slab = g>>1, half = g&1; lane's physical slot s = half*64+lane ->
// row r=s>>2, logical chunk cl=(s&3)^((r>>1)&3) (XOR source swizzle matched
// by cphi on the read side).
__device__ __forceinline__ void stage_tile(const f16* __restrict__ xh,
                                           const f16* __restrict__ aggh,
                                           f16* dst, long rowBase,
                                           int wv, int lane) {
  #pragma unroll
  for (int i = 0; i < 3; ++i) {
    int g = wv * 3 + i;
    int slab = g >> 1, half = g & 1;
    int s = half * 64 + lane;
    int r = s >> 2;
    int cl = (s & 3) ^ ((r >> 1) & 3);
    long grow = rowBase + r;
    const f16* ap = (slab < 4)
        ? (xh + grow * 128 + slab * 32 + cl * 8)
        : (aggh + grow * 256 + (slab - 4) * 32 + cl * 8);
    __builtin_amdgcn_global_load_lds((const as1_cvoid*)ap,
                                     (as3_void*)&dst[slab * 1024 + half * 512],
                                     16, 0, 0);
  }
}

// Persistent fused layer-1 GEMM (f16 MFMA) + layer-2 transform epilogue.
// 256 blocks x 512 threads (1/CU). 8 waves, wave = 32 rows x 32 cols.
// B fragments loaded ONCE (normal loads) then PINNED with identity asm
// (volatile, position-fixed): loop consumes asm results -> no remat, bf
// stays in 96 VGPRs across all ~12 tiles. A double-buffered LDS (2x24KB);
// per tile each wave issues 3 DMA for the NEXT tile, then s_waitcnt
// vmcnt(3) + s_barrier (counted vmcnt: next-tile loads stay in flight
// across the barrier). Last tile drains vmcnt(0).
// Fragment layouts (m89/m120-verified): A: m=lane&15, k=quad*8+j;
// B: n=lane&15, k=quad*8+j; C/D: col=lane&15, row=quad*4+reg.
__global__ __launch_bounds__(512, 2) void gemm_persist(
    const f16* __restrict__ xh, const f16* __restrict__ aggh,
    const f16* __restrict__ w1t,
    const float* __restrict__ b1, const float* __restrict__ w2s,
    const float* __restrict__ w2r, const float* __restrict__ b2,
    float* __restrict__ z2, float* __restrict__ out) {
  __shared__ __align__(16) f16 Ash[2][12 * 1024];   // 2 x 24 KB
  __shared__ float zbuf[8][32][6];                   // 6 KB
  const int t = threadIdx.x;
  const int lane = t & 63, wv = t >> 6;
  const int ml = lane & 15, quad = lane >> 4;
  const int cphi = quad ^ ((ml >> 1) & 3);           // swizzled chunk for frags
  const int bid = blockIdx.x;
  const int rem = NT - GB * TPB;                     // 53
  const int ntiles = TPB + (bid < rem ? 1 : 0);
  const int tile0  = bid * TPB + (bid < rem ? bid : rem);

  // ---- prologue: stage tile0 into buf0, then load + PIN B fragments.
  stage_tile(xh, aggh, &Ash[0][0], (long)tile0 * 32, wv, lane);

  const f16* bwv = w1t + (long)(wv * 32 + ml) * 32 + quad * 8;
  f16x8 bf[12][2];
  #pragma unroll
  for (int ks = 0; ks < 12; ++ks)
    #pragma unroll
    for (int nt = 0; nt < 2; ++nt)
      bf[ks][nt] = *(const f16x8*)(bwv + (long)ks * 8192 + nt * 512);
  // Identity pin: volatile asm is position-fixed here; loads must complete
  // before it (compiler inserts one vmcnt wait in the prologue); the loop
  // below consumes asm RESULTS, which LLVM cannot rematerialize.
  #pragma unroll
  for (int ks = 0; ks < 12; ++ks)
    #pragma unroll
    for (int nt = 0; nt < 2; ++nt)
      asm volatile("" : "+v"(bf[ks][nt]));

  for (int i = 0; i < ntiles; ++i) {
    const long rowBase = (long)(tile0 + i) * 32;
    // issue next tile's DMA into the other buffer; counted vmcnt keeps them
    // in flight across the barrier. Last tile: full drain.
    if (i + 1 < ntiles) {
      stage_tile(xh, aggh, &Ash[(i + 1) & 1][0], rowBase + 32, wv, lane);
      asm volatile("s_waitcnt vmcnt(3)" ::: "memory");
    } else {
      asm volatile("s_waitcnt vmcnt(0)" ::: "memory");
    }
    __builtin_amdgcn_s_barrier();

    // ---- K-loop: pure ds_read + MFMA (B held in registers)
    const f16* Ab = &Ash[i & 1][0];
    f32x4 acc[2][2];
    #pragma unroll
    for (int mt = 0; mt < 2; ++mt)
      #pragma unroll
      for (int nt = 0; nt < 2; ++nt) acc[mt][nt] = (f32x4)(0.f);

    #pragma unroll
    for (int ks = 0; ks < 12; ++ks) {
      f16x8 af[2];
      #pragma unroll
      for (int mt = 0; mt < 2; ++mt)
        af[mt] = *(const f16x8*)&Ab[ks * 1024 + ((mt * 16 + ml) * 4 + cphi) * 8];
      #pragma unroll
      for (int mt = 0; mt < 2; ++mt)
        #pragma unroll
        for (int nt = 0; nt < 2; ++nt)
          acc[mt][nt] = __builtin_amdgcn_mfma_f32_16x16x32_f16(af[mt], bf[ks][nt],
                                                               acc[mt][nt], 0, 0, 0);
    }

    // Epilogue: h = relu(acc + b1[col]); 6 dots over this wave's 32 cols;
    // reduce over the 16 ml-lanes; partials to zbuf[wv].
    #pragma unroll
    for (int mt = 0; mt < 2; ++mt) {
      float z[4][6];
      #pragma unroll
      for (int rr = 0; rr < 4; ++rr)
        #pragma unroll
        for (int p = 0; p < 6; ++p) z[rr][p] = 0.f;
      #pragma unroll
      for (int nt = 0; nt < 2; ++nt) {
        int col = wv * 32 + nt * 16 + ml;
        float bb = b1[col];
        float wA = w2r[col * 2 + 0];
        float wB = w2r[col * 2 + 1];
        float wC = w2r[512 + col * 2 + 0];
        float wD = w2r[512 + col * 2 + 1];
        float wE = w2s[col * 2 + 0];
        float wF = w2s[col * 2 + 1];
        #pragma unroll
        for (int rr = 0; rr < 4; ++rr) {
          float hh = acc[mt][nt][rr] + bb;
          hh = hh > 0.f ? hh : 0.f;
          z[rr][0] = fmaf(hh, wA, z[rr][0]);
          z[rr][1] = fmaf(hh, wB, z[rr][1]);
          z[rr][2] = fmaf(hh, wC, z[rr][2]);
          z[rr][3] = fmaf(hh, wD, z[rr][3]);
          z[rr][4] = fmaf(hh, wE, z[rr][4]);
          z[rr][5] = fmaf(hh, wF, z[rr][5]);
        }
      }
      #pragma unroll
      for (int rr = 0; rr < 4; ++rr)
        #pragma unroll
        for (int p = 0; p < 6; ++p) {
          float v = z[rr][p];
          v += __shfl_xor(v, 1);
          v += __shfl_xor(v, 2);
          v += __shfl_xor(v, 4);
          v += __shfl_xor(v, 8);
          if (ml == 0) zbuf[wv][mt * 16 + quad * 4 + rr][p] = v;
        }
    }
    asm volatile("s_waitcnt lgkmcnt(0)" ::: "memory");  // zbuf writes visible
    __builtin_amdgcn_s_barrier();
    if (t < 192) {
      int r = t / 6, p = t % 6;
      long grow = rowBase + r;
      float v = zbuf[0][r][p] + zbuf[1][r][p] + zbuf[2][r][p] + zbuf[3][r][p]
              + zbuf[4][r][p] + zbuf[5][r][p] + zbuf[6][r][p] + zbuf[7][r][p];
      if (p < 4) z2[grow * 4 + p] = v;
      else       out[grow * 2 + (p - 4)] = v + b2[p - 4];
    }
    // WAR safety across iterations: next iter's stage targets the buffer
    // read two iterations ago; the vmcnt+barrier at next iter top orders
    // all waves' current reads before any re-DMA. zbuf WAR likewise
    // separated by that barrier (reads land in regs before barrier).
  }
}

// 4 lanes per node: lane sub handles every-4th edge; reduce over sub.
__global__ void gather2(const float* __restrict__ z2, const int* __restrict__ off,
                        const int* __restrict__ srcs, float* __restrict__ out) {
  int tid = blockIdx.x * blockDim.x + threadIdx.x;
  int n = tid >> 2;
  if (n >= NN) return;
  int sub = tid & 3;
  int e0 = off[2 * n];
  int e1 = off[2 * n + 1];
  int e2 = off[2 * n + 2];
  float o0 = 0.f, o1 = 0.f;
  for (int e = e0 + sub; e < e1; e += 4) {
    float2 v = *(const float2*)(z2 + (long)srcs[e] * 4);
    o0 += v.x; o1 += v.y;
  }
  for (int e = e1 + sub; e < e2; e += 4) {
    float2 v = *(const float2*)(z2 + (long)srcs[e] * 4 + 2);
    o0 += v.x; o1 += v.y;
  }
  o0 += __shfl_xor(o0, 1); o1 += __shfl_xor(o1, 1);
  o0 += __shfl_xor(o0, 2); o1 += __shfl_xor(o1, 2);
  if (sub == 0) {
    out[n * 2 + 0] += o0;
    out[n * 2 + 1] += o1;
  }
}

extern "C" void kernel_launch(void* const* d_in, const int* in_sizes, int n_in,
                              void* d_out, int out_size, void* d_ws, size_t ws_size,
                              hipStream_t stream) {
  const float* x   = (const float*)d_in[0];
  const int*   ei  = (const int*)d_in[1];
  const int*   et  = (const int*)d_in[2];
  const float* w1s = (const float*)d_in[3];
  const float* w1r = (const float*)d_in[4];
  const float* b1  = (const float*)d_in[5];
  const float* w2s = (const float*)d_in[6];
  const float* w2r = (const float*)d_in[7];
  const float* b2  = (const float*)d_in[8];
  float* out = (float*)d_out;
  const int E = in_sizes[2];
  const int* src = ei;
  const int* dst = ei + E;

  f16*   aggh = (f16*)d_ws;                      // NN*256 f16   (51.2 MB)
  f16*   xh   = aggh + (size_t)NN * 256;         // NN*128 f16   (25.6 MB)
  f16*   w1t  = xh + (size_t)NN * 128;           // 12*256*32 f16 (0.2 MB)
  float* z2   = (float*)(w1t + 12 * 256 * 32);   // NN*4 f32     (1.6 MB)
  int*   ebuf = (int*)(z2 + (size_t)NN * 4);     // NB*CAP int   (10.5 MB)
  int*   srcs = ebuf + (size_t)NB * CAP;         // E int        (6.4 MB)
  int*   off  = srcs + E;                        // NR+1 int     (0.8 MB)
  int*   gbase  = off + NR + 1;                  // NB int
  int*   bstart = gbase + NB;                    // NB+1 int

  int nblk = (E + CHUNK - 1) / CHUNK;
  zero_small<<<1, 512, 0, stream>>>(gbase);
  bucketB<<<nblk, 256, 0, stream>>>(src, dst, et, gbase, ebuf, E);
  bscan<<<1, 512, 0, stream>>>(gbase, bstart);
  bucketC<<<NB, 256, 0, stream>>>(ebuf, gbase, bstart, off, srcs);

  int n4 = NN * 128 / 4;
  int ncvt = n4 + 12 * 256 * 32;
  cvt_all<<<(ncvt + 255) / 256, 256, 0, stream>>>((const float4*)x, xh,
                                                  w1s, w1r, w1t, n4);

  aggregate<<<(NN * 64 + 255) / 256, 256, 0, stream>>>(xh, off, srcs, aggh);

  gemm_persist<<<GB, 512, 0, stream>>>(xh, aggh, w1t, b1, w2s, w2r, b2,
                                       z2, out);

  gather2<<<(NN * 4 + 255) / 256, 256, 0, stream>>>(z2, off, srcs, out);
}

// Round 7
// 351.525 us; speedup vs baseline: 1.3755x; 1.0548x over previous
//
#include <hip/hip_runtime.h>

// HGIN_classifier: two relational-GIN layers (R=2), ReLU between.
// R21: R20 + A-fragment addressing fix.
// R20 failed correctness (absmax 74.5): LDA omitted the per-quad k-offset
// ko=quad*8 (it was implicit in the old LDS chunk swizzle, encoded via
// cphi; B's pointer had it, A's didn't) -> all quads read quad-0's k-slice.
// Theory unchanged (untested, not falsified): gemm is generic-latency-bound
// (~80 wave-us/tile across R14-R19 regardless of B residency; Mfma 6%,
// VALU 14%, HBM 4%, conflicts 0). Lever = resident waves. Drop LDS
// staging/DMA/barriers (A is L3-resident, B L2-resident); read fragments
// directly from cache with 1-deep register prefetch; LDS = 3KB zbuf;
// launch_bounds(256,4) = cap 128 VGPR = 16 waves/CU (~1.7x R14).
// Pipeline: zero_small -> bucketB -> bscan -> bucketC
//           cvt_all -> aggregate -> gemm_direct -> gather2

typedef _Float16 f16;
typedef _Float16 f16x2 __attribute__((ext_vector_type(2)));
typedef _Float16 f16x4 __attribute__((ext_vector_type(4)));
typedef _Float16 f16x8 __attribute__((ext_vector_type(8)));
typedef float    f32x4 __attribute__((ext_vector_type(4)));

constexpr int NN   = 100000;
constexpr int NR   = NN * 2;     // (node, relation) segments
constexpr int NB   = 512;        // coarse buckets (only 391 populated)
constexpr int BSH  = 9;          // bucket = seg >> BSH (512 segs/bucket)
constexpr int CAP  = 5120;       // slots/bucket: mean 4096, +16 sigma
constexpr int CHUNK = 2048;      // edges per block in bucketB (782 blocks)

__global__ void zero_small(int* __restrict__ gbase) {
  int t = threadIdx.x;
  if (t < NB) gbase[t] = t * CAP;
}

// packed edge: (src << 9) | (seg & 511)   [src < 2^23, fits int]
// scatter into capacity-strided ebuf; gbase[b] ends at b*CAP + count(b).
__global__ void bucketB(const int* __restrict__ src, const int* __restrict__ dst,
                        const int* __restrict__ et, int* __restrict__ gbase,
                        int* __restrict__ ebuf, int E) {
  __shared__ int h[NB], base[NB];
  int t = threadIdx.x;
  for (int b = t; b < NB; b += 256) h[b] = 0;
  __syncthreads();
  int lo = blockIdx.x * CHUNK, hi = min(E, lo + CHUNK);
  for (int e = lo + t; e < hi; e += 256)
    atomicAdd(&h[(dst[e] * 2 + et[e]) >> BSH], 1);
  __syncthreads();
  for (int b = t; b < NB; b += 256) {
    int c = h[b];
    base[b] = c ? atomicAdd(&gbase[b], c) : 0;
    h[b] = 0;
  }
  __syncthreads();
  for (int e = lo + t; e < hi; e += 256) {
    int seg = dst[e] * 2 + et[e];
    int b = seg >> BSH;
    int r = atomicAdd(&h[b], 1);
    ebuf[base[b] + r] = (src[e] << BSH) | (seg & (NB - 1));
  }
}

// dense prefix over bucket counts: bstart[b] = sum_{<b} (gbase - b*CAP)
__global__ void bscan(const int* __restrict__ gbase, int* __restrict__ bstart) {
  __shared__ int s[NB];
  int t = threadIdx.x;
  int v = gbase[t] - t * CAP;
  s[t] = v;
  __syncthreads();
  #pragma unroll
  for (int o = 1; o < NB; o <<= 1) {
    int u = (t >= o) ? s[t - o] : 0;
    __syncthreads();
    s[t] += u;
    __syncthreads();
  }
  bstart[t] = s[t] - v;
  if (t == NB - 1) bstart[NB] = s[t];
}

// One block per bucket: CSR off (dense, start-based) + dense srcs scatter.
__global__ void bucketC(const int* __restrict__ ebuf, const int* __restrict__ gbase,
                        const int* __restrict__ bstart,
                        int* __restrict__ off, int* __restrict__ srcs) {
  __shared__ int sh[NB], soff[NB], cnt[NB], tmp[256];
  int b = blockIdx.x, t = threadIdx.x;
  int lo = b * CAP, hi = gbase[b];
  int obase = bstart[b];
  for (int s0 = t; s0 < NB; s0 += 256) { sh[s0] = 0; cnt[s0] = 0; }
  __syncthreads();
  for (int e = lo + t; e < hi; e += 256)
    atomicAdd(&sh[ebuf[e] & (NB - 1)], 1);
  __syncthreads();
  int a0 = sh[2 * t], a1 = sh[2 * t + 1];
  tmp[t] = a0 + a1;
  __syncthreads();
  #pragma unroll
  for (int o = 1; o < 256; o <<= 1) {
    int u = (t >= o) ? tmp[t - o] : 0;
    __syncthreads();
    tmp[t] += u;
    __syncthreads();
  }
  int ex = tmp[t] - (a0 + a1);
  soff[2 * t] = ex;
  soff[2 * t + 1] = ex + a0;
  __syncthreads();
  int g0 = (b << BSH) + 2 * t;
  if (g0 <= NR)     off[g0]     = obase + soff[2 * t];
  if (g0 + 1 <= NR) off[g0 + 1] = obase + soff[2 * t + 1];
  for (int e = lo + t; e < hi; e += 256) {
    int p = ebuf[e];
    int s = p & (NB - 1);
    int r = atomicAdd(&cnt[s], 1);
    srcs[obase + soff[s] + r] = ((unsigned)p) >> BSH;
  }
}

// merged cast: x -> f16 and W1 -> k-step-major f16 repack.
// w1t[ks][n][ki] = f16(W[ks*32+ki][n]).
__global__ void cvt_all(const float4* __restrict__ xf, f16* __restrict__ xh,
                        const float* __restrict__ w1s, const float* __restrict__ w1r,
                        f16* __restrict__ w1t, int n4) {
  int i = blockIdx.x * blockDim.x + threadIdx.x;
  if (i < n4) {
    float4 v = xf[i];
    f16x4 h;
    h.x = (f16)v.x; h.y = (f16)v.y; h.z = (f16)v.z; h.w = (f16)v.w;
    *(f16x4*)(xh + (size_t)i * 4) = h;
  } else {
    int id = i - n4;
    if (id < 12 * 256 * 32) {
      int ks = id >> 13, rem = id & 8191;
      int n = rem >> 5, ki = rem & 31;
      int k = ks * 32 + ki;
      float v = (k < 128) ? w1s[k * 256 + n] : w1r[(k - 128) * 256 + n];
      w1t[id] = (f16)v;
    }
  }
}

// One wave per node. Lane-half h=lane>>5 processes edge e+h: one instruction
// loads 2 rows (32 lanes x f16x4 = 256B each). Halves merged via shfl_xor(32).
__global__ void aggregate(const f16* __restrict__ xh, const int* __restrict__ off,
                          const int* __restrict__ srcs, f16* __restrict__ aggh) {
  int w = (blockIdx.x * blockDim.x + threadIdx.x) >> 6;
  if (w >= NN) return;
  int lane = threadIdx.x & 63;
  int h = lane >> 5, c = lane & 31;
  int e0 = off[2 * w];
  int e1 = off[2 * w + 1];
  int e2 = off[2 * w + 2];
  float ax = 0.f, ay = 0.f, az = 0.f, aw = 0.f;
  float bx = 0.f, by = 0.f, bz = 0.f, bw = 0.f;

  int e = e0;
  for (; e + 7 < e1; e += 8) {
    f16x4 v0 = *(const f16x4*)(xh + (long)srcs[e     + h] * 128 + c * 4);
    f16x4 v1 = *(const f16x4*)(xh + (long)srcs[e + 2 + h] * 128 + c * 4);
    f16x4 v2 = *(const f16x4*)(xh + (long)srcs[e + 4 + h] * 128 + c * 4);
    f16x4 v3 = *(const f16x4*)(xh + (long)srcs[e + 6 + h] * 128 + c * 4);
    ax += (float)v0.x + (float)v1.x + (float)v2.x + (float)v3.x;
    ay += (float)v0.y + (float)v1.y + (float)v2.y + (float)v3.y;
    az += (float)v0.z + (float)v1.z + (float)v2.z + (float)v3.z;
    aw += (float)v0.w + (float)v1.w + (float)v2.w + (float)v3.w;
  }
  for (; e + 1 < e1; e += 2) {
    f16x4 v = *(const f16x4*)(xh + (long)srcs[e + h] * 128 + c * 4);
    ax += (float)v.x; ay += (float)v.y; az += (float)v.z; aw += (float)v.w;
  }
  if (e < e1) {
    f16x4 v = *(const f16x4*)(xh + (long)srcs[e] * 128 + c * 4);
    if (h == 0) { ax += (float)v.x; ay += (float)v.y; az += (float)v.z; aw += (float)v.w; }
  }
  e = e1;
  for (; e + 7 < e2; e += 8) {
    f16x4 v0 = *(const f16x4*)(xh + (long)srcs[e     + h] * 128 + c * 4);
    f16x4 v1 = *(const f16x4*)(xh + (long)srcs[e + 2 + h] * 128 + c * 4);
    f16x4 v2 = *(const f16x4*)(xh + (long)srcs[e + 4 + h] * 128 + c * 4);
    f16x4 v3 = *(const f16x4*)(xh + (long)srcs[e + 6 + h] * 128 + c * 4);
    bx += (float)v0.x + (float)v1.x + (float)v2.x + (float)v3.x;
    by += (float)v0.y + (float)v1.y + (float)v2.y + (float)v3.y;
    bz += (float)v0.z + (float)v1.z + (float)v2.z + (float)v3.z;
    bw += (float)v0.w + (float)v1.w + (float)v2.w + (float)v3.w;
  }
  for (; e + 1 < e2; e += 2) {
    f16x4 v = *(const f16x4*)(xh + (long)srcs[e + h] * 128 + c * 4);
    bx += (float)v.x; by += (float)v.y; bz += (float)v.z; bw += (float)v.w;
  }
  if (e < e2) {
    f16x4 v = *(const f16x4*)(xh + (long)srcs[e] * 128 + c * 4);
    if (h == 0) { bx += (float)v.x; by += (float)v.y; bz += (float)v.z; bw += (float)v.w; }
  }

  ax += __shfl_xor(ax, 32); ay += __shfl_xor(ay, 32);
  az += __shfl_xor(az, 32); aw += __shfl_xor(aw, 32);
  bx += __shfl_xor(bx, 32); by += __shfl_xor(by, 32);
  bz += __shfl_xor(bz, 32); bw += __shfl_xor(bw, 32);

  f16* row = aggh + (long)w * 256;
  f16x4 o;
  if (h == 0) {
    o.x = (f16)ax; o.y = (f16)ay; o.z = (f16)az; o.w = (f16)aw;
    *(f16x4*)(row + c * 4) = o;
  } else {
    o.x = (f16)bx; o.y = (f16)by; o.z = (f16)bz; o.w = (f16)bw;
    *(f16x4*)(row + 128 + c * 4) = o;
  }
}

// Fused layer-1 GEMM (f16 MFMA) + layer-2 transform epilogue — no LDS
// staging: fragments read directly from L3/L2 with 1-deep register
// prefetch. Grid 3125 x 256 thr (4 waves; wave = 32r x 64c; acc 2x4).
// LDS = 3KB zbuf only -> occupancy VGPR-capped; launch_bounds(256,4)
// = cap 128 VGPR = 16 waves/CU.
// Fragment layouts (m89/m120-verified): A: m=lane&15, k=quad*8+j;
// B: n=lane&15, k=quad*8+j; C/D: col=lane&15, row=quad*4+reg.
// A fragment address: row (rowBase+mt*16+ml), elements ks*32 + ko + 0..7
// where ko=quad*8 (R20 bug: ko was missing here).
__global__ __launch_bounds__(256, 4) void gemm_direct(
    const f16* __restrict__ xh, const f16* __restrict__ aggh,
    const f16* __restrict__ w1t,
    const float* __restrict__ b1, const float* __restrict__ w2s,
    const float* __restrict__ w2r, const float* __restrict__ b2,
    float* __restrict__ z2, float* __restrict__ out) {
  __shared__ float zbuf[4][32][6];                   // 3 KB
  const int t = threadIdx.x;
  const int lane = t & 63, wv = t >> 6;
  const int ml = lane & 15, quad = lane >> 4;
  const int ko = quad * 8;
  const long rowBase = (long)blockIdx.x * 32;

  // Per-lane A row bases (rows rowBase + mt*16 + ml), k<128 from xh,
  // k>=128 from aggh; ko folded in once.
  const f16* xr0 = xh   + (rowBase + ml) * 128 + ko;
  const f16* xr1 = xh   + (rowBase + 16 + ml) * 128 + ko;
  const f16* ar0 = aggh + (rowBase + ml) * 256 + ko;
  const f16* ar1 = aggh + (rowBase + 16 + ml) * 256 + ko;
  const f16* bwv = w1t + (long)(wv * 64 + ml) * 32 + ko;

  // Hoist epilogue weights (L2-resident, latency hides under K-loop).
  float bb[4], wA[4], wB[4], wC[4], wD[4], wE[4], wF[4];
  #pragma unroll
  for (int nt = 0; nt < 4; ++nt) {
    int col = wv * 64 + nt * 16 + ml;
    bb[nt] = b1[col];
    wA[nt] = w2r[col * 2 + 0];
    wB[nt] = w2r[col * 2 + 1];
    wC[nt] = w2r[512 + col * 2 + 0];
    wD[nt] = w2r[512 + col * 2 + 1];
    wE[nt] = w2s[col * 2 + 0];
    wF[nt] = w2s[col * 2 + 1];
  }

  f32x4 acc[2][4];
  #pragma unroll
  for (int mt = 0; mt < 2; ++mt)
    #pragma unroll
    for (int nt = 0; nt < 4; ++nt) acc[mt][nt] = (f32x4)(0.f);

  // ---- K-loop, fully unrolled, 1-deep register prefetch, no barriers.
#define LDA(d, K) do { \
    if ((K) < 4) { d[0] = *(const f16x8*)(xr0 + (K) * 32); \
                   d[1] = *(const f16x8*)(xr1 + (K) * 32); } \
    else         { d[0] = *(const f16x8*)(ar0 + ((K) - 4) * 32); \
                   d[1] = *(const f16x8*)(ar1 + ((K) - 4) * 32); } } while (0)
#define LDB(d, K) do { \
    _Pragma("unroll") \
    for (int nt = 0; nt < 4; ++nt) \
      d[nt] = *(const f16x8*)(bwv + (long)(K) * 8192 + nt * 512); } while (0)

  f16x8 afc[2], bfc[4], afn[2], bfn[4];
  LDA(afc, 0);
  LDB(bfc, 0);
  #pragma unroll
  for (int ks = 0; ks < 12; ++ks) {
    if (ks < 11) { LDA(afn, ks + 1); LDB(bfn, ks + 1); }   // issue next
    #pragma unroll
    for (int mt = 0; mt < 2; ++mt)
      #pragma unroll
      for (int nt = 0; nt < 4; ++nt)
        acc[mt][nt] = __builtin_amdgcn_mfma_f32_16x16x32_f16(afc[mt], bfc[nt],
                                                             acc[mt][nt], 0, 0, 0);
    if (ks < 11) {
      afc[0] = afn[0]; afc[1] = afn[1];
      #pragma unroll
      for (int nt = 0; nt < 4; ++nt) bfc[nt] = bfn[nt];
    }
  }
#undef LDA
#undef LDB

  // Epilogue: h = relu(acc + b1[col]); 6 dots over this wave's 64 cols;
  // reduce over the 16 ml-lanes; partials to zbuf[wv].
  #pragma unroll
  for (int mt = 0; mt < 2; ++mt) {
    float z[4][6];
    #pragma unroll
    for (int rr = 0; rr < 4; ++rr)
      #pragma unroll
      for (int p = 0; p < 6; ++p) z[rr][p] = 0.f;
    #pragma unroll
    for (int nt = 0; nt < 4; ++nt) {
      #pragma unroll
      for (int rr = 0; rr < 4; ++rr) {
        float hh = acc[mt][nt][rr] + bb[nt];
        hh = hh > 0.f ? hh : 0.f;
        z[rr][0] = fmaf(hh, wA[nt], z[rr][0]);
        z[rr][1] = fmaf(hh, wB[nt], z[rr][1]);
        z[rr][2] = fmaf(hh, wC[nt], z[rr][2]);
        z[rr][3] = fmaf(hh, wD[nt], z[rr][3]);
        z[rr][4] = fmaf(hh, wE[nt], z[rr][4]);
        z[rr][5] = fmaf(hh, wF[nt], z[rr][5]);
      }
    }
    #pragma unroll
    for (int rr = 0; rr < 4; ++rr)
      #pragma unroll
      for (int p = 0; p < 6; ++p) {
        float v = z[rr][p];
        v += __shfl_xor(v, 1);
        v += __shfl_xor(v, 2);
        v += __shfl_xor(v, 4);
        v += __shfl_xor(v, 8);
        if (ml == 0) zbuf[wv][mt * 16 + quad * 4 + rr][p] = v;
      }
  }
  __syncthreads();
  if (t < 192) {
    int r = t / 6, p = t % 6;
    long grow = rowBase + r;
    float v = zbuf[0][r][p] + zbuf[1][r][p] + zbuf[2][r][p] + zbuf[3][r][p];
    if (p < 4) z2[grow * 4 + p] = v;
    else       out[grow * 2 + (p - 4)] = v + b2[p - 4];
  }
}

// 4 lanes per node: lane sub handles every-4th edge; reduce over sub.
__global__ void gather2(const float* __restrict__ z2, const int* __restrict__ off,
                        const int* __restrict__ srcs, float* __restrict__ out) {
  int tid = blockIdx.x * blockDim.x + threadIdx.x;
  int n = tid >> 2;
  if (n >= NN) return;
  int sub = tid & 3;
  int e0 = off[2 * n];
  int e1 = off[2 * n + 1];
  int e2 = off[2 * n + 2];
  float o0 = 0.f, o1 = 0.f;
  for (int e = e0 + sub; e < e1; e += 4) {
    float2 v = *(const float2*)(z2 + (long)srcs[e] * 4);
    o0 += v.x; o1 += v.y;
  }
  for (int e = e1 + sub; e < e2; e += 4) {
    float2 v = *(const float2*)(z2 + (long)srcs[e] * 4 + 2);
    o0 += v.x; o1 += v.y;
  }
  o0 += __shfl_xor(o0, 1); o1 += __shfl_xor(o1, 1);
  o0 += __shfl_xor(o0, 2); o1 += __shfl_xor(o1, 2);
  if (sub == 0) {
    out[n * 2 + 0] += o0;
    out[n * 2 + 1] += o1;
  }
}

extern "C" void kernel_launch(void* const* d_in, const int* in_sizes, int n_in,
                              void* d_out, int out_size, void* d_ws, size_t ws_size,
                              hipStream_t stream) {
  const float* x   = (const float*)d_in[0];
  const int*   ei  = (const int*)d_in[1];
  const int*   et  = (const int*)d_in[2];
  const float* w1s = (const float*)d_in[3];
  const float* w1r = (const float*)d_in[4];
  const float* b1  = (const float*)d_in[5];
  const float* w2s = (const float*)d_in[6];
  const float* w2r = (const float*)d_in[7];
  const float* b2  = (const float*)d_in[8];
  float* out = (float*)d_out;
  const int E = in_sizes[2];
  const int* src = ei;
  const int* dst = ei + E;

  f16*   aggh = (f16*)d_ws;                      // NN*256 f16   (51.2 MB)
  f16*   xh   = aggh + (size_t)NN * 256;         // NN*128 f16   (25.6 MB)
  f16*   w1t  = xh + (size_t)NN * 128;           // 12*256*32 f16 (0.2 MB)
  float* z2   = (float*)(w1t + 12 * 256 * 32);   // NN*4 f32     (1.6 MB)
  int*   ebuf = (int*)(z2 + (size_t)NN * 4);     // NB*CAP int   (10.5 MB)
  int*   srcs = ebuf + (size_t)NB * CAP;         // E int        (6.4 MB)
  int*   off  = srcs + E;                        // NR+1 int     (0.8 MB)
  int*   gbase  = off + NR + 1;                  // NB int
  int*   bstart = gbase + NB;                    // NB+1 int

  int nblk = (E + CHUNK - 1) / CHUNK;
  zero_small<<<1, 512, 0, stream>>>(gbase);
  bucketB<<<nblk, 256, 0, stream>>>(src, dst, et, gbase, ebuf, E);
  bscan<<<1, 512, 0, stream>>>(gbase, bstart);
  bucketC<<<NB, 256, 0, stream>>>(ebuf, gbase, bstart, off, srcs);

  int n4 = NN * 128 / 4;
  int ncvt = n4 + 12 * 256 * 32;
  cvt_all<<<(ncvt + 255) / 256, 256, 0, stream>>>((const float4*)x, xh,
                                                  w1s, w1r, w1t, n4);

  aggregate<<<(NN * 64 + 255) / 256, 256, 0, stream>>>(xh, off, srcs, aggh);

  gemm_direct<<<NN / 32, 256, 0, stream>>>(xh, aggh, w1t, b1, w2s, w2r, b2,
                                           z2, out);

  gather2<<<(NN * 4 + 255) / 256, 256, 0, stream>>>(z2, off, srcs, out);
}

// Round 8
// 335.651 us; speedup vs baseline: 1.4406x; 1.0473x over previous
//
#include <hip/hip_runtime.h>

// HGIN_classifier: two relational-GIN layers (R=2), ReLU between.
// R22: (a) RESTORE R14 gemm verbatim (best of 7 attempts: 79.5us; every
// scheduler-fighting variant — reg-hoist R15/16, persistent R17-19,
// no-LDS direct R21 — landed 95-122us; compiler collapses manual prefetch
// to ~1-deep regardless). (b) EXPERIMENT: aggregate reshaped to one wave
// per (node,relation) SEGMENT: 200k waves x ~8 edges instead of 100k x 16.
// Theory: aggregate's 410MB random 256B-row gather from L3 (~600cy) is
// latency-bound; 2x TLP + half the serial chain -> ~0.55x its duration.
// Null result (total ~=326) => aggregate is L3-BW-bound; pivot elsewhere.
// Pipeline: zero_small -> bucketB -> bscan -> bucketC
//           cvt_all -> aggregate -> gemm_mfma -> gather2

typedef _Float16 f16;
typedef _Float16 f16x2 __attribute__((ext_vector_type(2)));
typedef _Float16 f16x4 __attribute__((ext_vector_type(4)));
typedef _Float16 f16x8 __attribute__((ext_vector_type(8)));
typedef float    f32x4 __attribute__((ext_vector_type(4)));
typedef __attribute__((address_space(3))) void       as3_void;
typedef __attribute__((address_space(1))) const void as1_cvoid;

constexpr int NN   = 100000;
constexpr int NR   = NN * 2;     // (node, relation) segments
constexpr int NB   = 512;        // coarse buckets (only 391 populated)
constexpr int BSH  = 9;          // bucket = seg >> BSH (512 segs/bucket)
constexpr int CAP  = 5120;       // slots/bucket: mean 4096, +16 sigma
constexpr int CHUNK = 2048;      // edges per block in bucketB (782 blocks)

__global__ void zero_small(int* __restrict__ gbase) {
  int t = threadIdx.x;
  if (t < NB) gbase[t] = t * CAP;
}

// packed edge: (src << 9) | (seg & 511)   [src < 2^23, fits int]
// scatter into capacity-strided ebuf; gbase[b] ends at b*CAP + count(b).
__global__ void bucketB(const int* __restrict__ src, const int* __restrict__ dst,
                        const int* __restrict__ et, int* __restrict__ gbase,
                        int* __restrict__ ebuf, int E) {
  __shared__ int h[NB], base[NB];
  int t = threadIdx.x;
  for (int b = t; b < NB; b += 256) h[b] = 0;
  __syncthreads();
  int lo = blockIdx.x * CHUNK, hi = min(E, lo + CHUNK);
  for (int e = lo + t; e < hi; e += 256)
    atomicAdd(&h[(dst[e] * 2 + et[e]) >> BSH], 1);
  __syncthreads();
  for (int b = t; b < NB; b += 256) {
    int c = h[b];
    base[b] = c ? atomicAdd(&gbase[b], c) : 0;
    h[b] = 0;
  }
  __syncthreads();
  for (int e = lo + t; e < hi; e += 256) {
    int seg = dst[e] * 2 + et[e];
    int b = seg >> BSH;
    int r = atomicAdd(&h[b], 1);
    ebuf[base[b] + r] = (src[e] << BSH) | (seg & (NB - 1));
  }
}

// dense prefix over bucket counts: bstart[b] = sum_{<b} (gbase - b*CAP)
__global__ void bscan(const int* __restrict__ gbase, int* __restrict__ bstart) {
  __shared__ int s[NB];
  int t = threadIdx.x;
  int v = gbase[t] - t * CAP;
  s[t] = v;
  __syncthreads();
  #pragma unroll
  for (int o = 1; o < NB; o <<= 1) {
    int u = (t >= o) ? s[t - o] : 0;
    __syncthreads();
    s[t] += u;
    __syncthreads();
  }
  bstart[t] = s[t] - v;
  if (t == NB - 1) bstart[NB] = s[t];
}

// One block per bucket: CSR off (dense, start-based) + dense srcs scatter.
__global__ void bucketC(const int* __restrict__ ebuf, const int* __restrict__ gbase,
                        const int* __restrict__ bstart,
                        int* __restrict__ off, int* __restrict__ srcs) {
  __shared__ int sh[NB], soff[NB], cnt[NB], tmp[256];
  int b = blockIdx.x, t = threadIdx.x;
  int lo = b * CAP, hi = gbase[b];
  int obase = bstart[b];
  for (int s0 = t; s0 < NB; s0 += 256) { sh[s0] = 0; cnt[s0] = 0; }
  __syncthreads();
  for (int e = lo + t; e < hi; e += 256)
    atomicAdd(&sh[ebuf[e] & (NB - 1)], 1);
  __syncthreads();
  int a0 = sh[2 * t], a1 = sh[2 * t + 1];
  tmp[t] = a0 + a1;
  __syncthreads();
  #pragma unroll
  for (int o = 1; o < 256; o <<= 1) {
    int u = (t >= o) ? tmp[t - o] : 0;
    __syncthreads();
    tmp[t] += u;
    __syncthreads();
  }
  int ex = tmp[t] - (a0 + a1);
  soff[2 * t] = ex;
  soff[2 * t + 1] = ex + a0;
  __syncthreads();
  int g0 = (b << BSH) + 2 * t;
  if (g0 <= NR)     off[g0]     = obase + soff[2 * t];
  if (g0 + 1 <= NR) off[g0 + 1] = obase + soff[2 * t + 1];
  for (int e = lo + t; e < hi; e += 256) {
    int p = ebuf[e];
    int s = p & (NB - 1);
    int r = atomicAdd(&cnt[s], 1);
    srcs[obase + soff[s] + r] = ((unsigned)p) >> BSH;
  }
}

// merged cast: x -> f16 and W1 -> k-step-major f16 repack.
// w1t[ks][n][ki] = f16(W[ks*32+ki][n]).
__global__ void cvt_all(const float4* __restrict__ xf, f16* __restrict__ xh,
                        const float* __restrict__ w1s, const float* __restrict__ w1r,
                        f16* __restrict__ w1t, int n4) {
  int i = blockIdx.x * blockDim.x + threadIdx.x;
  if (i < n4) {
    float4 v = xf[i];
    f16x4 h;
    h.x = (f16)v.x; h.y = (f16)v.y; h.z = (f16)v.z; h.w = (f16)v.w;
    *(f16x4*)(xh + (size_t)i * 4) = h;
  } else {
    int id = i - n4;
    if (id < 12 * 256 * 32) {
      int ks = id >> 13, rem = id & 8191;
      int n = rem >> 5, ki = rem & 31;
      int k = ks * 32 + ki;
      float v = (k < 128) ? w1s[k * 256 + n] : w1r[(k - 128) * 256 + n];
      w1t[id] = (f16)v;
    }
  }
}

// R22: one wave per (node,relation) SEGMENT (200k waves, ~8 edges each).
// Lane-half h processes edge e+h (one instr loads 2 rows: 32 lanes x f16x4).
// Halves merged via shfl_xor(32); h==0 half writes the segment's 256B row.
__global__ void aggregate(const f16* __restrict__ xh, const int* __restrict__ off,
                          const int* __restrict__ srcs, f16* __restrict__ aggh) {
  int s = (blockIdx.x * blockDim.x + threadIdx.x) >> 6;
  if (s >= NR) return;
  int lane = threadIdx.x & 63;
  int h = lane >> 5, c = lane & 31;
  int e0 = off[s];
  int e1 = off[s + 1];
  float ax = 0.f, ay = 0.f, az = 0.f, aw = 0.f;

  int e = e0;
  for (; e + 7 < e1; e += 8) {
    f16x4 v0 = *(const f16x4*)(xh + (long)srcs[e     + h] * 128 + c * 4);
    f16x4 v1 = *(const f16x4*)(xh + (long)srcs[e + 2 + h] * 128 + c * 4);
    f16x4 v2 = *(const f16x4*)(xh + (long)srcs[e + 4 + h] * 128 + c * 4);
    f16x4 v3 = *(const f16x4*)(xh + (long)srcs[e + 6 + h] * 128 + c * 4);
    ax += (float)v0.x + (float)v1.x + (float)v2.x + (float)v3.x;
    ay += (float)v0.y + (float)v1.y + (float)v2.y + (float)v3.y;
    az += (float)v0.z + (float)v1.z + (float)v2.z + (float)v3.z;
    aw += (float)v0.w + (float)v1.w + (float)v2.w + (float)v3.w;
  }
  for (; e + 1 < e1; e += 2) {
    f16x4 v = *(const f16x4*)(xh + (long)srcs[e + h] * 128 + c * 4);
    ax += (float)v.x; ay += (float)v.y; az += (float)v.z; aw += (float)v.w;
  }
  if (e < e1) {
    f16x4 v = *(const f16x4*)(xh + (long)srcs[e] * 128 + c * 4);
    if (h == 0) { ax += (float)v.x; ay += (float)v.y; az += (float)v.z; aw += (float)v.w; }
  }

  ax += __shfl_xor(ax, 32); ay += __shfl_xor(ay, 32);
  az += __shfl_xor(az, 32); aw += __shfl_xor(aw, 32);

  if (h == 0) {
    f16x4 o;
    o.x = (f16)ax; o.y = (f16)ay; o.z = (f16)az; o.w = (f16)aw;
    *(f16x4*)(aggh + (long)s * 128 + c * 4) = o;
  }
}

// Fused layer-1 GEMM (f16 MFMA) + layer-2 transform epilogue.
// [RESTORED R14 — best measured: 79.5us, VGPR 80, 24.6KB LDS, 6 blocks/CU]
// 32-row tile: A (32r x 384k = 24 KB) staged upfront via global_load_lds as
// 12 slabs x 2 KB; wave wv issues 6 DMA instrs ((slab,half) pairs). ONE
// barrier, then barrier-free unrolled K-loop: A from ds_read_b128 (XOR chunk
// swizzle, conflict-free), B direct from L2.
// Grid 3125 (NN/32 exact). 4 waves, wave = 32r x 64c (acc 2x4 = 32 VGPR).
// Fragment layouts (m89/m120-verified): A: m=lane&15, k=quad*8+j;
// B: n=lane&15, k=quad*8+j; C/D: col=lane&15, row=quad*4+reg.
__global__ __launch_bounds__(256) void gemm_mfma(
    const f16* __restrict__ xh, const f16* __restrict__ aggh,
    const f16* __restrict__ w1t,
    const float* __restrict__ b1, const float* __restrict__ w2s,
    const float* __restrict__ w2r, const float* __restrict__ b2,
    float* __restrict__ z2, float* __restrict__ out) {
  __shared__ __align__(16) f16 Ash[12 * 1024];    // 12 slabs x 2 KB = 24 KB
  float (*zbuf)[32][6] = (float (*)[32][6])(void*)Ash;  // aliased (3 KB)
  const int t = threadIdx.x;
  const int lane = t & 63, wv = t >> 6;
  const int ml = lane & 15, quad = lane >> 4;
  const int cphi = quad ^ ((ml >> 1) & 3);        // swizzled chunk for frags
  const long rowBase = (long)blockIdx.x * 32;

  // ---- upfront A staging: 24 wave-level DMA instrs, 6 per wave.
  #pragma unroll
  for (int i = 0; i < 6; ++i) {
    int g = wv * 6 + i;
    int slab = g >> 1, half = g & 1;
    int s = half * 64 + lane;
    int r = s >> 2;
    int cl = (s & 3) ^ ((r >> 1) & 3);
    long grow = rowBase + r;
    const f16* ap = (slab < 4)
        ? (xh + grow * 128 + slab * 32 + cl * 8)
        : (aggh + grow * 256 + (slab - 4) * 32 + cl * 8);
    __builtin_amdgcn_global_load_lds((const as1_cvoid*)ap,
                                     (as3_void*)&Ash[slab * 1024 + half * 512],
                                     16, 0, 0);
  }
  __syncthreads();                                  // drains DMA + barrier

  // ---- barrier-free K-loop
  const f16* bwv = w1t + (long)(wv * 64 + ml) * 32 + quad * 8;
  f32x4 acc[2][4];
  #pragma unroll
  for (int mt = 0; mt < 2; ++mt)
    #pragma unroll
    for (int nt = 0; nt < 4; ++nt) acc[mt][nt] = (f32x4)(0.f);

  #pragma unroll
  for (int ks = 0; ks < 12; ++ks) {
    f16x8 af[2], bf[4];
    #pragma unroll
    for (int nt = 0; nt < 4; ++nt)
      bf[nt] = *(const f16x8*)(bwv + (long)ks * 8192 + nt * 16 * 32);
    #pragma unroll
    for (int mt = 0; mt < 2; ++mt)
      af[mt] = *(const f16x8*)&Ash[ks * 1024 + ((mt * 16 + ml) * 4 + cphi) * 8];
    #pragma unroll
    for (int mt = 0; mt < 2; ++mt)
      #pragma unroll
      for (int nt = 0; nt < 4; ++nt)
        acc[mt][nt] = __builtin_amdgcn_mfma_f32_16x16x32_f16(af[mt], bf[nt],
                                                             acc[mt][nt], 0, 0, 0);
  }
  __syncthreads();   // all Ash reads done before zbuf (aliased) writes

  // Epilogue: h = relu(acc + b1[col]); 6 dots over this wave's 64 cols;
  // reduce over the 16 ml-lanes; partials to zbuf[wv] (aliased onto Ash).
  #pragma unroll
  for (int mt = 0; mt < 2; ++mt) {
    float z[4][6];
    #pragma unroll
    for (int rr = 0; rr < 4; ++rr)
      #pragma unroll
      for (int p = 0; p < 6; ++p) z[rr][p] = 0.f;
    #pragma unroll
    for (int nt = 0; nt < 4; ++nt) {
      int col = wv * 64 + nt * 16 + ml;
      float bb = b1[col];
      float wA = w2r[col * 2 + 0];
      float wB = w2r[col * 2 + 1];
      float wC = w2r[512 + col * 2 + 0];
      float wD = w2r[512 + col * 2 + 1];
      float wE = w2s[col * 2 + 0];
      float wF = w2s[col * 2 + 1];
      #pragma unroll
      for (int rr = 0; rr < 4; ++rr) {
        float hh = acc[mt][nt][rr] + bb;
        hh = hh > 0.f ? hh : 0.f;
        z[rr][0] = fmaf(hh, wA, z[rr][0]);
        z[rr][1] = fmaf(hh, wB, z[rr][1]);
        z[rr][2] = fmaf(hh, wC, z[rr][2]);
        z[rr][3] = fmaf(hh, wD, z[rr][3]);
        z[rr][4] = fmaf(hh, wE, z[rr][4]);
        z[rr][5] = fmaf(hh, wF, z[rr][5]);
      }
    }
    #pragma unroll
    for (int rr = 0; rr < 4; ++rr)
      #pragma unroll
      for (int p = 0; p < 6; ++p) {
        float v = z[rr][p];
        v += __shfl_xor(v, 1);
        v += __shfl_xor(v, 2);
        v += __shfl_xor(v, 4);
        v += __shfl_xor(v, 8);
        if (ml == 0) zbuf[wv][mt * 16 + quad * 4 + rr][p] = v;
      }
  }
  __syncthreads();
  if (t < 192) {
    int r = t / 6, p = t % 6;
    long grow = rowBase + r;
    float v = zbuf[0][r][p] + zbuf[1][r][p] + zbuf[2][r][p] + zbuf[3][r][p];
    if (p < 4) z2[grow * 4 + p] = v;
    else       out[grow * 2 + (p - 4)] = v + b2[p - 4];
  }
}

// 4 lanes per node: lane sub handles every-4th edge; reduce over sub.
__global__ void gather2(const float* __restrict__ z2, const int* __restrict__ off,
                        const int* __restrict__ srcs, float* __restrict__ out) {
  int tid = blockIdx.x * blockDim.x + threadIdx.x;
  int n = tid >> 2;
  if (n >= NN) return;
  int sub = tid & 3;
  int e0 = off[2 * n];
  int e1 = off[2 * n + 1];
  int e2 = off[2 * n + 2];
  float o0 = 0.f, o1 = 0.f;
  for (int e = e0 + sub; e < e1; e += 4) {
    float2 v = *(const float2*)(z2 + (long)srcs[e] * 4);
    o0 += v.x; o1 += v.y;
  }
  for (int e = e1 + sub; e < e2; e += 4) {
    float2 v = *(const float2*)(z2 + (long)srcs[e] * 4 + 2);
    o0 += v.x; o1 += v.y;
  }
  o0 += __shfl_xor(o0, 1); o1 += __shfl_xor(o1, 1);
  o0 += __shfl_xor(o0, 2); o1 += __shfl_xor(o1, 2);
  if (sub == 0) {
    out[n * 2 + 0] += o0;
    out[n * 2 + 1] += o1;
  }
}

extern "C" void kernel_launch(void* const* d_in, const int* in_sizes, int n_in,
                              void* d_out, int out_size, void* d_ws, size_t ws_size,
                              hipStream_t stream) {
  const float* x   = (const float*)d_in[0];
  const int*   ei  = (const int*)d_in[1];
  const int*   et  = (const int*)d_in[2];
  const float* w1s = (const float*)d_in[3];
  const float* w1r = (const float*)d_in[4];
  const float* b1  = (const float*)d_in[5];
  const float* w2s = (const float*)d_in[6];
  const float* w2r = (const float*)d_in[7];
  const float* b2  = (const float*)d_in[8];
  float* out = (float*)d_out;
  const int E = in_sizes[2];
  const int* src = ei;
  const int* dst = ei + E;

  f16*   aggh = (f16*)d_ws;                      // NN*256 f16   (51.2 MB)
  f16*   xh   = aggh + (size_t)NN * 256;         // NN*128 f16   (25.6 MB)
  f16*   w1t  = xh + (size_t)NN * 128;           // 12*256*32 f16 (0.2 MB)
  float* z2   = (float*)(w1t + 12 * 256 * 32);   // NN*4 f32     (1.6 MB)
  int*   ebuf = (int*)(z2 + (size_t)NN * 4);     // NB*CAP int   (10.5 MB)
  int*   srcs = ebuf + (size_t)NB * CAP;         // E int        (6.4 MB)
  int*   off  = srcs + E;                        // NR+1 int     (0.8 MB)
  int*   gbase  = off + NR + 1;                  // NB int
  int*   bstart = gbase + NB;                    // NB+1 int

  int nblk = (E + CHUNK - 1) / CHUNK;
  zero_small<<<1, 512, 0, stream>>>(gbase);
  bucketB<<<nblk, 256, 0, stream>>>(src, dst, et, gbase, ebuf, E);
  bscan<<<1, 512, 0, stream>>>(gbase, bstart);
  bucketC<<<NB, 256, 0, stream>>>(ebuf, gbase, bstart, off, srcs);

  int n4 = NN * 128 / 4;
  int ncvt = n4 + 12 * 256 * 32;
  cvt_all<<<(ncvt + 255) / 256, 256, 0, stream>>>((const float4*)x, xh,
                                                  w1s, w1r, w1t, n4);

  aggregate<<<(NR * 64 + 255) / 256, 256, 0, stream>>>(xh, off, srcs, aggh);

  gemm_mfma<<<NN / 32, 256, 0, stream>>>(xh, aggh, w1t, b1, w2s, w2r, b2,
                                         z2, out);

  gather2<<<(NN * 4 + 255) / 256, 256, 0, stream>>>(z2, off, srcs, out);
}